// Round 2
// baseline (2614.346 us; speedup 1.0000x reference)
//
#include <hip/hip_runtime.h>
#include <hip/hip_bf16.h>
#include <math.h>

typedef __hip_bfloat16 bf16;
typedef float  floatx16 __attribute__((ext_vector_type(16)));
typedef short  short8   __attribute__((ext_vector_type(8)));

#define Bn 4
#define NF 64
#define Hn 192
#define Wn 192
#define HWn (Hn*Wn)

// ---- weight pool element offsets (bf16 elements, relative to WPOOL) ----
#define WA_OC1  0
#define WA_OC2  73728
#define WA_FC   110592
#define WA_CAS1 147456
#define WA_CAS2 221184
#define WA_D1O  258048
#define WA_CDO  405504
#define WP_D1   552960
#define WP_CD   589824
// ---- bias pool float offsets ----
#define B_OC1  0
#define B_OC2  64
#define B_FC   128
#define B_CAS1 192
#define B_CAS2 256
#define B_D1O  320
#define B_CDO  536
#define B_D1P  752
#define B_CDP  816
// ---- ws byte offsets ----
#define BIAS_OFF  1024
#define WPOOL_OFF 5120
#define BUF_OFF   1261568          // 4K aligned, past weight pool
#define FEAT_BYTES 18874368        // 4*64*36864*2

__device__ __forceinline__ float b2f(bf16 v){ return __bfloat162float(v); }
__device__ __forceinline__ bf16  f2b(float v){ return __float2bfloat16(v); }
__device__ __forceinline__ float us2f(unsigned short u){ return __uint_as_float(((unsigned)u) << 16); }
__device__ __forceinline__ float ld(const void* p, size_t i, int f32){
    if (f32) return ((const float*)p)[i];
    return b2f(((const bf16*)p)[i]);
}

union B8 { uint2 u2[2]; uint4 u4; short8 s8; };
union V8 { uint4 u4; unsigned short us[8]; bf16 h[8]; };

struct P20 { const void* p[20]; int n[20]; };

// ---------------------------------------------------------------------------
// Dtype probe (established: inputs fp32-in-memory, bf16-valued)
// ---------------------------------------------------------------------------
__global__ void detect_kernel(P20 a, int* __restrict__ flags){
    int t = threadIdx.x;
    if (t >= 20) return;
    const unsigned short* u = (const unsigned short*)a.p[t];
    int n = a.n[t]; if (n > 512) n = 512;
    int f32 = 0;
    for (int i = 0; i < n; ++i){
        float v = __uint_as_float(((unsigned)u[i]) << 16);
        if (!(fabsf(v) < 1e3f)) f32 = 1;
    }
    flags[t] = f32;
}

// ---------------------------------------------------------------------------
// Prep: 3x3 conv weights -> bf16 MFMA A-frag layout, tap-major K.
// ---------------------------------------------------------------------------
__global__ void prep_convA(const void* __restrict__ src, const int* __restrict__ flags,
                           int fi, bf16* __restrict__ dst, int Cin, int CoutReal, int OCB)
{
    int idx = blockIdx.x*256 + threadIdx.x;
    int KK = Cin >> 4;
    int total = OCB*9*KK*512;
    if (idx >= total) return;
    int j  = idx & 7;
    int ko = (idx>>3) & 1;
    int m  = (idx>>4) & 31;
    int rest = idx >> 9;
    int kk = rest % KK; rest /= KK;
    int tap = rest % 9;
    int ocb = rest / 9;
    int oc = ocb*32 + m;
    int ci = kk*16 + ko*8 + j;
    float v = 0.f;
    if (oc < CoutReal) v = ld(src, ((size_t)oc*Cin + ci)*9 + tap, flags[fi]);
    dst[idx] = f2b(v);
}

// ---------------------------------------------------------------------------
// Prep: DCN projection weights -> A-frag layout with PERMUTED K:
//   k' = (dg*9 + tap)*8 + cg   (cg contiguous -> vector LDS sample slots)
//   original k = (dg*8 + cg)*9 + tap
// ---------------------------------------------------------------------------
__global__ void prep_projA(const void* __restrict__ src, const int* __restrict__ flags,
                           int fi, bf16* __restrict__ dst)
{
    int idx = blockIdx.x*256 + threadIdx.x;
    if (idx >= 2*36*512) return;
    int j  = idx & 7;
    int ko = (idx>>3) & 1;
    int m  = (idx>>4) & 31;
    int rest = idx >> 9;
    int kk = rest % 36;
    int ocb = rest / 36;
    int oc = ocb*32 + m;
    int kp   = kk*16 + ko*8 + j;   // permuted K index
    int slot = kp >> 3;            // dg*9+tap
    int cg   = kp & 7;
    int dg   = slot / 9;
    int tap  = slot - dg*9;
    int k    = (dg*8 + cg)*9 + tap;
    dst[idx] = f2b(ld(src, (size_t)oc*576 + k, flags[fi]));
}

// ---------------------------------------------------------------------------
// Prep: biases -> fp32 pool
// ---------------------------------------------------------------------------
__global__ void prep_bias(P20 a, const int* __restrict__ flags, float* __restrict__ bp){
    int t = threadIdx.x;
    const int src[9] = {3,5,11,13,15,7,17,9,19};
    const int off[9] = {B_OC1,B_OC2,B_FC,B_CAS1,B_CAS2,B_D1O,B_CDO,B_D1P,B_CDP};
    const int sz[9]  = {64,64,64,64,64,216,216,64,64};
    for (int s = 0; s < 9; ++s)
        if (t < sz[s]) bp[off[s] + t] = ld(a.p[src[s]], t, flags[src[s]]);
}

// ---------------------------------------------------------------------------
// Pack: x [B][64][HW] (fp32 or bf16) -> xi [B][HW][64] bf16 (channel-interleaved)
// Tiled transpose: 64px x 64ch per block, LDS staged, vectorized loads.
// ---------------------------------------------------------------------------
__global__ __launch_bounds__(256)
void pack_x(const void* __restrict__ src, const int* __restrict__ flags, int fi,
            bf16* __restrict__ dst)
{
    __shared__ bf16 s[64*65];            // [ci][px], pad 65 breaks bank stride
    const int b    = blockIdx.y;
    const int pix0 = blockIdx.x * 64;
    const int t    = threadIdx.x;
    const int f    = (fi >= 0) ? flags[fi] : 0;

    const int px8 = (t & 7) * 8;
    const int ci0 = t >> 3;              // 0..31
#pragma unroll
    for (int it = 0; it < 2; ++it){
        int ci = ci0 + it*32;
        size_t g = ((size_t)b*NF + ci)*HWn + pix0 + px8;
        if (f){
            float4 a0 = *(const float4*)((const float*)src + g);
            float4 a1 = *(const float4*)((const float*)src + g + 4);
            bf16* sp = &s[ci*65 + px8];
            sp[0]=f2b(a0.x); sp[1]=f2b(a0.y); sp[2]=f2b(a0.z); sp[3]=f2b(a0.w);
            sp[4]=f2b(a1.x); sp[5]=f2b(a1.y); sp[6]=f2b(a1.z); sp[7]=f2b(a1.w);
        } else {
            V8 v; v.u4 = *(const uint4*)((const bf16*)src + g);
            bf16* sp = &s[ci*65 + px8];
#pragma unroll
            for (int j = 0; j < 8; ++j) sp[j] = v.h[j];
        }
    }
    __syncthreads();

    const int px  = t >> 2;
    const int ch0 = (t & 3) * 16;
    V8 o0, o1;
#pragma unroll
    for (int j = 0; j < 8; ++j){
        o0.h[j] = s[(ch0 + j)*65 + px];
        o1.h[j] = s[(ch0 + 8 + j)*65 + px];
    }
    bf16* dp = dst + ((size_t)b*HWn + pix0 + px)*64 + ch0;
    *(uint4*)(dp)     = o0.u4;
    *(uint4*)(dp + 8) = o1.u4;
}

// ---------------------------------------------------------------------------
// MFMA implicit-GEMM 3x3 conv (pad=1). Block: 256 thr = 4 waves, tile 64oc x 64px.
// ACT: 0=none, 1=lrelu, 2=dcn-offset epilogue (sigmoid for oc>=144, raw below).
// ---------------------------------------------------------------------------
__global__ __launch_bounds__(256)
void conv_mfma(const void* __restrict__ inA, const void* __restrict__ inB,
               const bf16* __restrict__ wA, const float* __restrict__ bias,
               bf16* __restrict__ out,
               int CinA, int CinB, int CoutReal, int OutChStore, int ACT,
               const int* __restrict__ flags, int fiA, int fiB)
{
    extern __shared__ __align__(16) char smem_raw[];
    bf16* s_in = (bf16*)smem_raw;

    const int CinT  = CinA + CinB;
    const int ciPad = CinT + 4;                 // 68 or 132
    const int b     = blockIdx.z;
    const int pix0  = blockIdx.x * 64;          // 64 px, same row (192%64==0)
    const int h     = pix0 / Wn;
    const int x0    = pix0 - h*Wn;
    const int ocBase= blockIdx.y * 64;
    const int tid   = threadIdx.x;
    const int fA = (fiA>=0)?flags[fiA]:0;
    const int fB = (fiB>=0)?flags[fiB]:0;

    // ---- stage patch: rows h-1..h+1, cols x0-1..x0+64, all CinT channels ----
    const int total = 3*66*CinT;
    for (int idx = tid; idx < total; idx += 256){
        int c  = idx % 66;
        int r  = idx / 66;
        int ky = r % 3;
        int ci = r / 3;
        int y  = h - 1 + ky;
        int xx = x0 - 1 + c;
        float v = 0.f;
        if ((unsigned)y < (unsigned)Hn && (unsigned)xx < (unsigned)Wn){
            if (ci < CinA) v = ld(inA, ((size_t)b*CinA + ci)*HWn + y*Wn + xx, fA);
            else           v = ld(inB, ((size_t)b*CinB + (ci-CinA))*HWn + y*Wn + xx, fB);
        }
        s_in[(ky*66 + c)*ciPad + ci] = f2b(v);
    }
    __syncthreads();

    // ---- MFMA main loop ----
    const int w    = tid >> 6;
    const int lane = tid & 63;
    const int m    = lane & 31;
    const int half = lane >> 5;
    const int och  = (w >> 1) * 32;
    const int pxh  = (w & 1) * 32;
    const int KK   = CinT >> 4;
    const int ocb  = blockIdx.y*2 + (w >> 1);

    floatx16 acc;
#pragma unroll
    for (int r = 0; r < 16; ++r) acc[r] = 0.f;

    const bf16* wAb = wA + ((size_t)ocb*9*KK)*512 + m*16 + half*8;
    const int col0 = pxh + m;

#pragma unroll
    for (int tap = 0; tap < 9; ++tap){
        const int ky = tap/3, kx = tap - (tap/3)*3;
        const bf16* srow = s_in + (ky*66 + col0 + kx)*ciPad + half*8;
        for (int kk = 0; kk < KK; ++kk){
            B8 ba; ba.u4 = *(const uint4*)(wAb + (size_t)(tap*KK + kk)*512);
            B8 bb;
            const bf16* sp = srow + kk*16;
            bb.u2[0] = *(const uint2*)(sp);
            bb.u2[1] = *(const uint2*)(sp + 4);
            acc = __builtin_amdgcn_mfma_f32_32x32x16_bf16(ba.s8, bb.s8, acc, 0, 0, 0);
        }
    }

    // ---- epilogue ----
    const int pxo = pix0 + pxh + m;
#pragma unroll
    for (int r = 0; r < 16; ++r){
        int row = (r & 3) + 8*(r >> 2) + 4*half;
        int oc  = ocBase + och + row;
        if (oc < CoutReal){
            float v = acc[r] + bias[oc];
            if (ACT == 1) v = (v >= 0.f) ? v : 0.1f*v;
            else if (ACT == 2 && oc >= 144) v = 1.f/(1.f + expf(-v));  // mask sigmoid
            out[((size_t)b*OutChStore + oc)*HWn + pxo] = f2b(v);
        }
    }
}

// ---------------------------------------------------------------------------
// DCN sample + MFMA projection. Block: 256 thr, 64 px (one row segment).
// Phase C (chain-broken): ALL 54 offset values prefetched into registers
//   (independent coalesced loads, one latency exposure), then the 18-slot
//   sampling loop FULLY UNROLLED so all 72 corner gathers are independent
//   ILP the scheduler can pipeline. launch_bounds(256,2) lifts the VGPR cap
//   (occupancy is LDS-bound at 2 blocks/CU regardless).
// Phase D: out[64oc][64px] = W(64x576) x samples via 32x32x16 MFMA,
//          K permuted to (dg*9+tap)*8+cg (matches prep_projA).
// ---------------------------------------------------------------------------
__global__ __launch_bounds__(256, 2)
void dcn_mfma(const bf16* __restrict__ xi,     // interleaved [B][HW][64] bf16
              const bf16* __restrict__ offs,   // [B][216][HW] bf16 (masks sigmoided)
              const bf16* __restrict__ wP,     // A-frag layout, K permuted
              const float* __restrict__ pbias, // [64]
              void* __restrict__ out, int outF32, int ACT)
{
    // px stride = 73 slots * 16B: odd 16B-chunk stride spreads banks.
    __shared__ __align__(16) bf16 s_samp[64*584];

    const int b    = blockIdx.y;
    const int pix0 = blockIdx.x * 64;
    const int h    = pix0 / Wn;
    const int x0   = pix0 - h*Wn;
    const int tid  = threadIdx.x;

    // ---- Phase C: vectorized bilinear sampling, chain-broken ----
    {
        const int px = tid & 63;
        const int wq = tid >> 6;
        const size_t obase = (size_t)b*216*HWn + pix0 + px;
        const float fx = (float)(x0 + px - 1);
        const bf16* xb = xi + (size_t)b*HWn*64;
        const uint4 z4 = {0u,0u,0u,0u};

        // Prefetch all 54 offsets (independent, coalesced -> deep pipeline)
        float ody[18], odx[18], omk[18];
#pragma unroll
        for (int i = 0; i < 18; ++i){
            const int dg  = wq*2 + (i/9);
            const int tap = i % 9;
            ody[i] = b2f(offs[obase + (size_t)(dg*18 + tap*2    )*HWn]);
            odx[i] = b2f(offs[obase + (size_t)(dg*18 + tap*2 + 1)*HWn]);
            omk[i] = b2f(offs[obase + (size_t)(144 + dg*9 + tap )*HWn]);
        }

#pragma unroll
        for (int i = 0; i < 18; ++i){
            const int dg  = wq*2 + (i/9);
            const int tap = i % 9;
            const int ky  = tap / 3;
            const int kx  = tap - ky*3;
            const int dt  = dg*9 + tap;     // == wq*18 + i
            float py  = ody[i] + (float)(h - 1 + ky);
            float pxx = odx[i] + fx + (float)kx;
            float mk  = omk[i];
            float y0f = floorf(py), x0f = floorf(pxx);
            int   y0  = (int)y0f,   xi0 = (int)x0f;
            float wy  = py - y0f,   wx  = pxx - x0f;
            float w00 = (1.f-wy)*(1.f-wx)*mk, w01 = (1.f-wy)*wx*mk;
            float w10 = wy*(1.f-wx)*mk,       w11 = wy*wx*mk;
            bool y0v = (unsigned)y0     < (unsigned)Hn;
            bool y1v = (unsigned)(y0+1) < (unsigned)Hn;
            bool x0v = (unsigned)xi0     < (unsigned)Wn;
            bool x1v = (unsigned)(xi0+1) < (unsigned)Wn;
            long long r0 = (long long)y0*Wn + xi0;
            const bf16* p00 = xb + r0*64 + dg*8;
            const bf16* p10 = p00 + (long long)Wn*64;
            V8 c00, c01, c10, c11, o;
            c00.u4 = (y0v && x0v) ? *(const uint4*)(p00)      : z4;
            c01.u4 = (y0v && x1v) ? *(const uint4*)(p00 + 64) : z4;
            c10.u4 = (y1v && x0v) ? *(const uint4*)(p10)      : z4;
            c11.u4 = (y1v && x1v) ? *(const uint4*)(p10 + 64) : z4;
#pragma unroll
            for (int j = 0; j < 8; ++j){
                float v = w00*us2f(c00.us[j]) + w01*us2f(c01.us[j])
                        + w10*us2f(c10.us[j]) + w11*us2f(c11.us[j]);
                o.h[j] = f2b(v);
            }
            *(uint4*)&s_samp[px*584 + dt*8] = o.u4;
        }
    }
    __syncthreads();

    // ---- Phase D: projection GEMM ----
    const int w    = tid >> 6;
    const int lane = tid & 63;
    const int m    = lane & 31;
    const int half = lane >> 5;
    const int och  = (w >> 1) * 32;
    const int pxh  = (w & 1) * 32;

    floatx16 acc;
#pragma unroll
    for (int r = 0; r < 16; ++r) acc[r] = 0.f;

    const bf16* wPb  = wP + ((size_t)(w>>1)*36)*512 + m*16 + half*8;
    const bf16* srow = s_samp + (pxh + m)*584 + half*8;
#pragma unroll 4
    for (int kk = 0; kk < 36; ++kk){
        B8 ba; ba.u4 = *(const uint4*)(wPb + (size_t)kk*512);
        B8 bb; bb.u4 = *(const uint4*)(srow + kk*16);
        acc = __builtin_amdgcn_mfma_f32_32x32x16_bf16(ba.s8, bb.s8, acc, 0, 0, 0);
    }

    const int pxo = pix0 + pxh + m;
#pragma unroll
    for (int r = 0; r < 16; ++r){
        int row = (r & 3) + 8*(r >> 2) + 4*half;
        int oc  = och + row;
        float v = acc[r] + pbias[oc];
        if (ACT) v = (v >= 0.f) ? v : 0.1f*v;
        size_t oi = ((size_t)b*NF + oc)*HWn + pxo;
        if (outF32) ((float*)out)[oi] = v;
        else        ((bf16*) out)[oi] = f2b(v);
    }
}

// ---------------------------------------------------------------------------
extern "C" void kernel_launch(void* const* d_in, const int* in_sizes, int n_in,
                              void* d_out, int out_size, void* d_ws, size_t ws_size,
                              hipStream_t stream)
{
    enum { I_NBR=0, I_REF=1, I_OC1W=2, I_OC2W=4, I_D1OW=6, I_D1W=8, I_FCW=10,
           I_C1W=12, I_C2W=14, I_CDOW=16, I_CDW=18 };

    int*   flags = (int*)d_ws;
    float* bp    = (float*)((char*)d_ws + BIAS_OFF);
    bf16*  wp    = (bf16*) ((char*)d_ws + WPOOL_OFF);
    bf16*  t1    = (bf16*) ((char*)d_ws + BUF_OFF);
    bf16*  f1    = (bf16*) ((char*)d_ws + BUF_OFF + FEAT_BYTES);
    bf16*  offs  = (bf16*) ((char*)d_ws + BUF_OFF + 2*(size_t)FEAT_BYTES);
    bf16*  t0    = (bf16*) d_out;   // fp32-sized out doubles as bf16 scratch
    bf16*  nbr_i = (bf16*)((char*)d_out + FEAT_BYTES);  // second half of d_out
    bf16*  f1i   = t1;              // t1 region dead after step 8

    P20 a;
    for (int i = 0; i < 20; ++i){ a.p[i] = d_in[i]; a.n[i] = in_sizes[i]; }

    detect_kernel<<<1, 64, 0, stream>>>(a, flags);
    prep_bias<<<1, 256, 0, stream>>>(a, flags, bp);
    prep_convA<<<288, 256, 0, stream>>>(d_in[I_OC1W], flags, I_OC1W, wp+WA_OC1, 128, 64, 2);
    prep_convA<<<144, 256, 0, stream>>>(d_in[I_OC2W], flags, I_OC2W, wp+WA_OC2,  64, 64, 2);
    prep_convA<<<144, 256, 0, stream>>>(d_in[I_FCW],  flags, I_FCW,  wp+WA_FC,   64, 64, 2);
    prep_convA<<<288, 256, 0, stream>>>(d_in[I_C1W],  flags, I_C1W,  wp+WA_CAS1,128, 64, 2);
    prep_convA<<<144, 256, 0, stream>>>(d_in[I_C2W],  flags, I_C2W,  wp+WA_CAS2, 64, 64, 2);
    prep_convA<<<576, 256, 0, stream>>>(d_in[I_D1OW], flags, I_D1OW, wp+WA_D1O,  64, 216, 8);
    prep_convA<<<576, 256, 0, stream>>>(d_in[I_CDOW], flags, I_CDOW, wp+WA_CDO,  64, 216, 8);
    prep_projA<<<144, 256, 0, stream>>>(d_in[I_D1W],  flags, I_D1W,  wp+WP_D1);
    prep_projA<<<144, 256, 0, stream>>>(d_in[I_CDW],  flags, I_CDW,  wp+WP_CD);

    dim3 blk(256,1,1);
    const int smem64  = 3*66*68*2;    // 26928 B
    const int smem128 = 3*66*132*2;   // 52272 B
    dim3 g64 (576, 1, Bn);
    dim3 g216(576, 4, Bn);
    dim3 gD  (576, Bn, 1);
    dim3 gP  (576, Bn, 1);

    // 0. nbr_i = pack(nbr) channel-interleaved bf16 (lives in d_out 2nd half)
    pack_x<<<gP, blk, 0, stream>>>(d_in[I_NBR], flags, I_NBR, nbr_i);
    // 1. t0 = lrelu(conv(cat(nbr,ref), oc1))
    conv_mfma<<<g64, blk, smem128, stream>>>(d_in[I_NBR], d_in[I_REF], wp+WA_OC1, bp+B_OC1,
        t0, 64, 64, 64, 64, 1, flags, I_NBR, I_REF);
    // 2. t1 = lrelu(conv(t0, oc2))
    conv_mfma<<<g64, blk, smem64, stream>>>(t0, nullptr, wp+WA_OC2, bp+B_OC2,
        t1, 64, 0, 64, 64, 1, flags, -1, -1);
    // 3. offs = conv(t1, d1o)  [offsets raw, masks sigmoided via ACT=2]
    conv_mfma<<<g216, blk, smem64, stream>>>(t1, nullptr, wp+WA_D1O, bp+B_D1O,
        offs, 64, 0, 216, 216, 2, flags, -1, -1);
    // 4. t1 = dcn(x=nbr_i, offs; proj d1)
    dcn_mfma<<<gD, blk, 0, stream>>>(nbr_i, offs, wp+WP_D1, bp+B_D1P,
        t1, 0, 0);
    // 5. f1 = conv(t1, fc)  (no act)
    conv_mfma<<<g64, blk, smem64, stream>>>(t1, nullptr, wp+WA_FC, bp+B_FC,
        f1, 64, 0, 64, 64, 0, flags, -1, -1);
    // 6. t0 = lrelu(conv(cat(f1, ref), cas1))
    conv_mfma<<<g64, blk, smem128, stream>>>(f1, d_in[I_REF], wp+WA_CAS1, bp+B_CAS1,
        t0, 64, 64, 64, 64, 1, flags, -1, I_REF);
    // 7. t1 = lrelu(conv(t0, cas2))
    conv_mfma<<<g64, blk, smem64, stream>>>(t0, nullptr, wp+WA_CAS2, bp+B_CAS2,
        t1, 64, 0, 64, 64, 1, flags, -1, -1);
    // 8. offs = conv(t1, cdo)  [ACT=2]
    conv_mfma<<<g216, blk, smem64, stream>>>(t1, nullptr, wp+WA_CDO, bp+B_CDO,
        offs, 64, 0, 216, 216, 2, flags, -1, -1);
    // 8b. f1i = pack(f1) channel-interleaved (into t1 region, dead after step 8)
    pack_x<<<gP, blk, 0, stream>>>(f1, flags, -1, f1i);
    // 9. d_out = lrelu(dcn(x=f1i, offs; proj cd))  fp32
    dcn_mfma<<<gD, blk, 0, stream>>>(f1i, offs, wp+WP_CD, bp+B_CDP,
        d_out, 1, 1);
}

// Round 3
// 2576.444 us; speedup vs baseline: 1.0147x; 1.0147x over previous
//
#include <hip/hip_runtime.h>
#include <hip/hip_bf16.h>
#include <math.h>

typedef __hip_bfloat16 bf16;
typedef float  floatx16 __attribute__((ext_vector_type(16)));
typedef short  short8   __attribute__((ext_vector_type(8)));

#define Bn 4
#define NF 64
#define Hn 192
#define Wn 192
#define HWn (Hn*Wn)

// ---- weight pool element offsets (bf16 elements, relative to WPOOL) ----
#define WA_OC1  0
#define WA_OC2  73728
#define WA_FC   110592
#define WA_CAS1 147456
#define WA_CAS2 221184
#define WA_D1O  258048
#define WA_CDO  405504
#define WP_D1   552960
#define WP_CD   589824
// ---- bias pool float offsets ----
#define B_OC1  0
#define B_OC2  64
#define B_FC   128
#define B_CAS1 192
#define B_CAS2 256
#define B_D1O  320
#define B_CDO  536
#define B_D1P  752
#define B_CDP  816
// ---- ws byte offsets ----
#define BIAS_OFF  1024
#define WPOOL_OFF 5120
#define BUF_OFF   1261568          // 4K aligned, past weight pool
#define FEAT_BYTES 18874368        // 4*64*36864*2

// LDS px stride for dcn sample buffer: 296 elems = 592 B = 37 x 16B chunks
// (odd chunk count spreads banks; multiple of 16B keeps b128 alignment)
#define SSTR 296

__device__ __forceinline__ float b2f(bf16 v){ return __bfloat162float(v); }
__device__ __forceinline__ bf16  f2b(float v){ return __float2bfloat16(v); }
__device__ __forceinline__ float us2f(unsigned short u){ return __uint_as_float(((unsigned)u) << 16); }
__device__ __forceinline__ float ld(const void* p, size_t i, int f32){
    if (f32) return ((const float*)p)[i];
    return b2f(((const bf16*)p)[i]);
}

union B8 { uint2 u2[2]; uint4 u4; short8 s8; };
union V8 { uint4 u4; unsigned short us[8]; bf16 h[8]; };

struct P20 { const void* p[20]; int n[20]; };

// ---------------------------------------------------------------------------
// Dtype probe (established: inputs fp32-in-memory, bf16-valued)
// ---------------------------------------------------------------------------
__global__ void detect_kernel(P20 a, int* __restrict__ flags){
    int t = threadIdx.x;
    if (t >= 20) return;
    const unsigned short* u = (const unsigned short*)a.p[t];
    int n = a.n[t]; if (n > 512) n = 512;
    int f32 = 0;
    for (int i = 0; i < n; ++i){
        float v = __uint_as_float(((unsigned)u[i]) << 16);
        if (!(fabsf(v) < 1e3f)) f32 = 1;
    }
    flags[t] = f32;
}

// ---------------------------------------------------------------------------
// Prep: 3x3 conv weights -> bf16 MFMA A-frag layout, tap-major K.
// ---------------------------------------------------------------------------
__global__ void prep_convA(const void* __restrict__ src, const int* __restrict__ flags,
                           int fi, bf16* __restrict__ dst, int Cin, int CoutReal, int OCB)
{
    int idx = blockIdx.x*256 + threadIdx.x;
    int KK = Cin >> 4;
    int total = OCB*9*KK*512;
    if (idx >= total) return;
    int j  = idx & 7;
    int ko = (idx>>3) & 1;
    int m  = (idx>>4) & 31;
    int rest = idx >> 9;
    int kk = rest % KK; rest /= KK;
    int tap = rest % 9;
    int ocb = rest / 9;
    int oc = ocb*32 + m;
    int ci = kk*16 + ko*8 + j;
    float v = 0.f;
    if (oc < CoutReal) v = ld(src, ((size_t)oc*Cin + ci)*9 + tap, flags[fi]);
    dst[idx] = f2b(v);
}

// ---------------------------------------------------------------------------
// Prep: DCN projection weights -> A-frag layout with PERMUTED K:
//   k' = (dg*9 + tap)*8 + cg   (cg contiguous -> vector LDS sample slots)
//   original k = (dg*8 + cg)*9 + tap
// ---------------------------------------------------------------------------
__global__ void prep_projA(const void* __restrict__ src, const int* __restrict__ flags,
                           int fi, bf16* __restrict__ dst)
{
    int idx = blockIdx.x*256 + threadIdx.x;
    if (idx >= 2*36*512) return;
    int j  = idx & 7;
    int ko = (idx>>3) & 1;
    int m  = (idx>>4) & 31;
    int rest = idx >> 9;
    int kk = rest % 36;
    int ocb = rest / 36;
    int oc = ocb*32 + m;
    int kp   = kk*16 + ko*8 + j;   // permuted K index
    int slot = kp >> 3;            // dg*9+tap
    int cg   = kp & 7;
    int dg   = slot / 9;
    int tap  = slot - dg*9;
    int k    = (dg*8 + cg)*9 + tap;
    dst[idx] = f2b(ld(src, (size_t)oc*576 + k, flags[fi]));
}

// ---------------------------------------------------------------------------
// Prep: biases -> fp32 pool
// ---------------------------------------------------------------------------
__global__ void prep_bias(P20 a, const int* __restrict__ flags, float* __restrict__ bp){
    int t = threadIdx.x;
    const int src[9] = {3,5,11,13,15,7,17,9,19};
    const int off[9] = {B_OC1,B_OC2,B_FC,B_CAS1,B_CAS2,B_D1O,B_CDO,B_D1P,B_CDP};
    const int sz[9]  = {64,64,64,64,64,216,216,64,64};
    for (int s = 0; s < 9; ++s)
        if (t < sz[s]) bp[off[s] + t] = ld(a.p[src[s]], t, flags[src[s]]);
}

// ---------------------------------------------------------------------------
// Pack: x [B][64][HW] (fp32 or bf16) -> xi [B][HW][64] bf16 (channel-interleaved)
// Tiled transpose: 64px x 64ch per block, LDS staged, vectorized loads.
// ---------------------------------------------------------------------------
__global__ __launch_bounds__(256)
void pack_x(const void* __restrict__ src, const int* __restrict__ flags, int fi,
            bf16* __restrict__ dst)
{
    __shared__ bf16 s[64*65];            // [ci][px], pad 65 breaks bank stride
    const int b    = blockIdx.y;
    const int pix0 = blockIdx.x * 64;
    const int t    = threadIdx.x;
    const int f    = (fi >= 0) ? flags[fi] : 0;

    const int px8 = (t & 7) * 8;
    const int ci0 = t >> 3;              // 0..31
#pragma unroll
    for (int it = 0; it < 2; ++it){
        int ci = ci0 + it*32;
        size_t g = ((size_t)b*NF + ci)*HWn + pix0 + px8;
        if (f){
            float4 a0 = *(const float4*)((const float*)src + g);
            float4 a1 = *(const float4*)((const float*)src + g + 4);
            bf16* sp = &s[ci*65 + px8];
            sp[0]=f2b(a0.x); sp[1]=f2b(a0.y); sp[2]=f2b(a0.z); sp[3]=f2b(a0.w);
            sp[4]=f2b(a1.x); sp[5]=f2b(a1.y); sp[6]=f2b(a1.z); sp[7]=f2b(a1.w);
        } else {
            V8 v; v.u4 = *(const uint4*)((const bf16*)src + g);
            bf16* sp = &s[ci*65 + px8];
#pragma unroll
            for (int j = 0; j < 8; ++j) sp[j] = v.h[j];
        }
    }
    __syncthreads();

    const int px  = t >> 2;
    const int ch0 = (t & 3) * 16;
    V8 o0, o1;
#pragma unroll
    for (int j = 0; j < 8; ++j){
        o0.h[j] = s[(ch0 + j)*65 + px];
        o1.h[j] = s[(ch0 + 8 + j)*65 + px];
    }
    bf16* dp = dst + ((size_t)b*HWn + pix0 + px)*64 + ch0;
    *(uint4*)(dp)     = o0.u4;
    *(uint4*)(dp + 8) = o1.u4;
}

// ---------------------------------------------------------------------------
// MFMA implicit-GEMM 3x3 conv (pad=1). Block: 256 thr = 4 waves, tile 64oc x 64px.
// ACT: 0=none, 1=lrelu, 2=dcn-offset epilogue (sigmoid for oc>=144, raw below).
// ---------------------------------------------------------------------------
__global__ __launch_bounds__(256)
void conv_mfma(const void* __restrict__ inA, const void* __restrict__ inB,
               const bf16* __restrict__ wA, const float* __restrict__ bias,
               bf16* __restrict__ out,
               int CinA, int CinB, int CoutReal, int OutChStore, int ACT,
               const int* __restrict__ flags, int fiA, int fiB)
{
    extern __shared__ __align__(16) char smem_raw[];
    bf16* s_in = (bf16*)smem_raw;

    const int CinT  = CinA + CinB;
    const int ciPad = CinT + 4;                 // 68 or 132
    const int b     = blockIdx.z;
    const int pix0  = blockIdx.x * 64;          // 64 px, same row (192%64==0)
    const int h     = pix0 / Wn;
    const int x0    = pix0 - h*Wn;
    const int ocBase= blockIdx.y * 64;
    const int tid   = threadIdx.x;
    const int fA = (fiA>=0)?flags[fiA]:0;
    const int fB = (fiB>=0)?flags[fiB]:0;

    // ---- stage patch: rows h-1..h+1, cols x0-1..x0+64, all CinT channels ----
    const int total = 3*66*CinT;
    for (int idx = tid; idx < total; idx += 256){
        int c  = idx % 66;
        int r  = idx / 66;
        int ky = r % 3;
        int ci = r / 3;
        int y  = h - 1 + ky;
        int xx = x0 - 1 + c;
        float v = 0.f;
        if ((unsigned)y < (unsigned)Hn && (unsigned)xx < (unsigned)Wn){
            if (ci < CinA) v = ld(inA, ((size_t)b*CinA + ci)*HWn + y*Wn + xx, fA);
            else           v = ld(inB, ((size_t)b*CinB + (ci-CinA))*HWn + y*Wn + xx, fB);
        }
        s_in[(ky*66 + c)*ciPad + ci] = f2b(v);
    }
    __syncthreads();

    // ---- MFMA main loop ----
    const int w    = tid >> 6;
    const int lane = tid & 63;
    const int m    = lane & 31;
    const int half = lane >> 5;
    const int och  = (w >> 1) * 32;
    const int pxh  = (w & 1) * 32;
    const int KK   = CinT >> 4;
    const int ocb  = blockIdx.y*2 + (w >> 1);

    floatx16 acc;
#pragma unroll
    for (int r = 0; r < 16; ++r) acc[r] = 0.f;

    const bf16* wAb = wA + ((size_t)ocb*9*KK)*512 + m*16 + half*8;
    const int col0 = pxh + m;

#pragma unroll
    for (int tap = 0; tap < 9; ++tap){
        const int ky = tap/3, kx = tap - (tap/3)*3;
        const bf16* srow = s_in + (ky*66 + col0 + kx)*ciPad + half*8;
        for (int kk = 0; kk < KK; ++kk){
            B8 ba; ba.u4 = *(const uint4*)(wAb + (size_t)(tap*KK + kk)*512);
            B8 bb;
            const bf16* sp = srow + kk*16;
            bb.u2[0] = *(const uint2*)(sp);
            bb.u2[1] = *(const uint2*)(sp + 4);
            acc = __builtin_amdgcn_mfma_f32_32x32x16_bf16(ba.s8, bb.s8, acc, 0, 0, 0);
        }
    }

    // ---- epilogue ----
    const int pxo = pix0 + pxh + m;
#pragma unroll
    for (int r = 0; r < 16; ++r){
        int row = (r & 3) + 8*(r >> 2) + 4*half;
        int oc  = ocBase + och + row;
        if (oc < CoutReal){
            float v = acc[r] + bias[oc];
            if (ACT == 1) v = (v >= 0.f) ? v : 0.1f*v;
            else if (ACT == 2 && oc >= 144) v = 1.f/(1.f + expf(-v));  // mask sigmoid
            out[((size_t)b*OutChStore + oc)*HWn + pxo] = f2b(v);
        }
    }
}

// ---------------------------------------------------------------------------
// DCN sample + MFMA projection, SPLIT-K for occupancy.
// LDS sample buffer halved (64px x 296 = 37,888 B -> 4 blocks/CU, 16 waves)
// by processing deform groups in two passes: {sample dg0-3, sync, 18 MFMA,
// sync} then {sample dg4-7, sync, 18 MFMA}. MFMA util is ~0.7% so the extra
// serialization is free; the point is 2x resident waves issuing gathers.
// Per pass each wave samples ONE dg (9 taps), offsets prefetched to regs.
// ---------------------------------------------------------------------------
__global__ __launch_bounds__(256, 4)
void dcn_mfma(const bf16* __restrict__ xi,     // interleaved [B][HW][64] bf16
              const bf16* __restrict__ offs,   // [B][216][HW] bf16 (masks sigmoided)
              const bf16* __restrict__ wP,     // A-frag layout, K permuted
              const float* __restrict__ pbias, // [64]
              void* __restrict__ out, int outF32, int ACT)
{
    __shared__ __align__(16) bf16 s_samp[64*SSTR];

    const int b    = blockIdx.y;
    const int pix0 = blockIdx.x * 64;
    const int h    = pix0 / Wn;
    const int x0   = pix0 - h*Wn;
    const int tid  = threadIdx.x;

    const int px   = tid & 63;
    const int wq   = tid >> 6;
    const int m    = px & 31;       // also MFMA m
    const int half = px >> 5;
    const int och  = (wq >> 1) * 32;
    const int pxh  = (wq & 1) * 32;

    const size_t obase = (size_t)b*216*HWn + pix0 + px;
    const float fx = (float)(x0 + px - 1);
    const bf16* xb = xi + (size_t)b*HWn*64;
    const uint4 z4 = {0u,0u,0u,0u};

    const bf16* wPb  = wP + ((size_t)(wq>>1)*36)*512 + m*16 + half*8;
    const bf16* srow = s_samp + (pxh + m)*SSTR + half*8;

    floatx16 acc;
#pragma unroll
    for (int r = 0; r < 16; ++r) acc[r] = 0.f;

#pragma unroll
    for (int pass = 0; pass < 2; ++pass){
        const int dg = pass*4 + wq;          // one deform group per wave

        // ---- Phase C: prefetch 27 offsets, then 9 taps of sampling ----
        float ody[9], odx[9], omk[9];
#pragma unroll
        for (int i = 0; i < 9; ++i){
            ody[i] = b2f(offs[obase + (size_t)(dg*18 + i*2    )*HWn]);
            odx[i] = b2f(offs[obase + (size_t)(dg*18 + i*2 + 1)*HWn]);
            omk[i] = b2f(offs[obase + (size_t)(144 + dg*9 + i )*HWn]);
        }

#pragma unroll
        for (int i = 0; i < 9; ++i){
            const int ky  = i / 3;
            const int kx  = i - ky*3;
            const int dt2 = wq*9 + i;        // slot within this pass [0,36)
            float py  = ody[i] + (float)(h - 1 + ky);
            float pxx = odx[i] + fx + (float)kx;
            float mk  = omk[i];
            float y0f = floorf(py), x0f = floorf(pxx);
            int   y0  = (int)y0f,   xi0 = (int)x0f;
            float wy  = py - y0f,   wx  = pxx - x0f;
            float w00 = (1.f-wy)*(1.f-wx)*mk, w01 = (1.f-wy)*wx*mk;
            float w10 = wy*(1.f-wx)*mk,       w11 = wy*wx*mk;
            bool y0v = (unsigned)y0     < (unsigned)Hn;
            bool y1v = (unsigned)(y0+1) < (unsigned)Hn;
            bool x0v = (unsigned)xi0     < (unsigned)Wn;
            bool x1v = (unsigned)(xi0+1) < (unsigned)Wn;
            long long r0 = (long long)y0*Wn + xi0;
            const bf16* p00 = xb + r0*64 + dg*8;
            const bf16* p10 = p00 + (long long)Wn*64;
            V8 c00, c01, c10, c11, o;
            c00.u4 = (y0v && x0v) ? *(const uint4*)(p00)      : z4;
            c01.u4 = (y0v && x1v) ? *(const uint4*)(p00 + 64) : z4;
            c10.u4 = (y1v && x0v) ? *(const uint4*)(p10)      : z4;
            c11.u4 = (y1v && x1v) ? *(const uint4*)(p10 + 64) : z4;
#pragma unroll
            for (int j = 0; j < 8; ++j){
                float v = w00*us2f(c00.us[j]) + w01*us2f(c01.us[j])
                        + w10*us2f(c10.us[j]) + w11*us2f(c11.us[j]);
                o.h[j] = f2b(v);
            }
            *(uint4*)&s_samp[px*SSTR + dt2*8] = o.u4;
        }
        __syncthreads();

        // ---- Phase D: 18 MFMAs over this pass's K-half ----
#pragma unroll 3
        for (int kk = 0; kk < 18; ++kk){
            B8 ba; ba.u4 = *(const uint4*)(wPb + (size_t)(pass*18 + kk)*512);
            B8 bb; bb.u4 = *(const uint4*)(srow + kk*16);
            acc = __builtin_amdgcn_mfma_f32_32x32x16_bf16(ba.s8, bb.s8, acc, 0, 0, 0);
        }
        if (pass == 0) __syncthreads();      // protect LDS before overwrite
    }

    // ---- epilogue ----
    const int pxo = pix0 + pxh + m;
#pragma unroll
    for (int r = 0; r < 16; ++r){
        int row = (r & 3) + 8*(r >> 2) + 4*half;
        int oc  = och + row;
        float v = acc[r] + pbias[oc];
        if (ACT) v = (v >= 0.f) ? v : 0.1f*v;
        size_t oi = ((size_t)b*NF + oc)*HWn + pxo;
        if (outF32) ((float*)out)[oi] = v;
        else        ((bf16*) out)[oi] = f2b(v);
    }
}

// ---------------------------------------------------------------------------
extern "C" void kernel_launch(void* const* d_in, const int* in_sizes, int n_in,
                              void* d_out, int out_size, void* d_ws, size_t ws_size,
                              hipStream_t stream)
{
    enum { I_NBR=0, I_REF=1, I_OC1W=2, I_OC2W=4, I_D1OW=6, I_D1W=8, I_FCW=10,
           I_C1W=12, I_C2W=14, I_CDOW=16, I_CDW=18 };

    int*   flags = (int*)d_ws;
    float* bp    = (float*)((char*)d_ws + BIAS_OFF);
    bf16*  wp    = (bf16*) ((char*)d_ws + WPOOL_OFF);
    bf16*  t1    = (bf16*) ((char*)d_ws + BUF_OFF);
    bf16*  f1    = (bf16*) ((char*)d_ws + BUF_OFF + FEAT_BYTES);
    bf16*  offs  = (bf16*) ((char*)d_ws + BUF_OFF + 2*(size_t)FEAT_BYTES);
    bf16*  t0    = (bf16*) d_out;   // fp32-sized out doubles as bf16 scratch
    bf16*  nbr_i = (bf16*)((char*)d_out + FEAT_BYTES);  // second half of d_out
    bf16*  f1i   = t1;              // t1 region dead after step 8

    P20 a;
    for (int i = 0; i < 20; ++i){ a.p[i] = d_in[i]; a.n[i] = in_sizes[i]; }

    detect_kernel<<<1, 64, 0, stream>>>(a, flags);
    prep_bias<<<1, 256, 0, stream>>>(a, flags, bp);
    prep_convA<<<288, 256, 0, stream>>>(d_in[I_OC1W], flags, I_OC1W, wp+WA_OC1, 128, 64, 2);
    prep_convA<<<144, 256, 0, stream>>>(d_in[I_OC2W], flags, I_OC2W, wp+WA_OC2,  64, 64, 2);
    prep_convA<<<144, 256, 0, stream>>>(d_in[I_FCW],  flags, I_FCW,  wp+WA_FC,   64, 64, 2);
    prep_convA<<<288, 256, 0, stream>>>(d_in[I_C1W],  flags, I_C1W,  wp+WA_CAS1,128, 64, 2);
    prep_convA<<<144, 256, 0, stream>>>(d_in[I_C2W],  flags, I_C2W,  wp+WA_CAS2, 64, 64, 2);
    prep_convA<<<576, 256, 0, stream>>>(d_in[I_D1OW], flags, I_D1OW, wp+WA_D1O,  64, 216, 8);
    prep_convA<<<576, 256, 0, stream>>>(d_in[I_CDOW], flags, I_CDOW, wp+WA_CDO,  64, 216, 8);
    prep_projA<<<144, 256, 0, stream>>>(d_in[I_D1W],  flags, I_D1W,  wp+WP_D1);
    prep_projA<<<144, 256, 0, stream>>>(d_in[I_CDW],  flags, I_CDW,  wp+WP_CD);

    dim3 blk(256,1,1);
    const int smem64  = 3*66*68*2;    // 26928 B
    const int smem128 = 3*66*132*2;   // 52272 B
    dim3 g64 (576, 1, Bn);
    dim3 g216(576, 4, Bn);
    dim3 gD  (576, Bn, 1);
    dim3 gP  (576, Bn, 1);

    // 0. nbr_i = pack(nbr) channel-interleaved bf16 (lives in d_out 2nd half)
    pack_x<<<gP, blk, 0, stream>>>(d_in[I_NBR], flags, I_NBR, nbr_i);
    // 1. t0 = lrelu(conv(cat(nbr,ref), oc1))
    conv_mfma<<<g64, blk, smem128, stream>>>(d_in[I_NBR], d_in[I_REF], wp+WA_OC1, bp+B_OC1,
        t0, 64, 64, 64, 64, 1, flags, I_NBR, I_REF);
    // 2. t1 = lrelu(conv(t0, oc2))
    conv_mfma<<<g64, blk, smem64, stream>>>(t0, nullptr, wp+WA_OC2, bp+B_OC2,
        t1, 64, 0, 64, 64, 1, flags, -1, -1);
    // 3. offs = conv(t1, d1o)  [offsets raw, masks sigmoided via ACT=2]
    conv_mfma<<<g216, blk, smem64, stream>>>(t1, nullptr, wp+WA_D1O, bp+B_D1O,
        offs, 64, 0, 216, 216, 2, flags, -1, -1);
    // 4. t1 = dcn(x=nbr_i, offs; proj d1)
    dcn_mfma<<<gD, blk, 0, stream>>>(nbr_i, offs, wp+WP_D1, bp+B_D1P,
        t1, 0, 0);
    // 5. f1 = conv(t1, fc)  (no act)
    conv_mfma<<<g64, blk, smem64, stream>>>(t1, nullptr, wp+WA_FC, bp+B_FC,
        f1, 64, 0, 64, 64, 0, flags, -1, -1);
    // 6. t0 = lrelu(conv(cat(f1, ref), cas1))
    conv_mfma<<<g64, blk, smem128, stream>>>(f1, d_in[I_REF], wp+WA_CAS1, bp+B_CAS1,
        t0, 64, 64, 64, 64, 1, flags, -1, I_REF);
    // 7. t1 = lrelu(conv(t0, cas2))
    conv_mfma<<<g64, blk, smem64, stream>>>(t0, nullptr, wp+WA_CAS2, bp+B_CAS2,
        t1, 64, 0, 64, 64, 1, flags, -1, -1);
    // 8. offs = conv(t1, cdo)  [ACT=2]
    conv_mfma<<<g216, blk, smem64, stream>>>(t1, nullptr, wp+WA_CDO, bp+B_CDO,
        offs, 64, 0, 216, 216, 2, flags, -1, -1);
    // 8b. f1i = pack(f1) channel-interleaved (into t1 region, dead after step 8)
    pack_x<<<gP, blk, 0, stream>>>(f1, flags, -1, f1i);
    // 9. d_out = lrelu(dcn(x=f1i, offs; proj cd))  fp32
    dcn_mfma<<<gD, blk, 0, stream>>>(f1i, offs, wp+WP_CD, bp+B_CDP,
        d_out, 1, 1);
}

// Round 5
// 1557.163 us; speedup vs baseline: 1.6789x; 1.6546x over previous
//
#include <hip/hip_runtime.h>
#include <hip/hip_bf16.h>
#include <math.h>

typedef __hip_bfloat16 bf16;
typedef float  floatx16 __attribute__((ext_vector_type(16)));
typedef short  short8   __attribute__((ext_vector_type(8)));

#define Bn 4
#define NF 64
#define Hn 192
#define Wn 192
#define HWn (Hn*Wn)

// ---- weight pool element offsets (bf16 elements, relative to WPOOL) ----
#define WA_OC1  0
#define WA_OC2  73728
#define WA_FC   110592
#define WA_CAS1 147456
#define WA_CAS2 221184
#define WA_D1O  258048
#define WA_CDO  405504
#define WP_D1   552960
#define WP_CD   589824
// ---- bias pool float offsets ----
#define B_OC1  0
#define B_OC2  64
#define B_FC   128
#define B_CAS1 192
#define B_CAS2 256
#define B_D1O  320
#define B_CDO  536
#define B_D1P  752
#define B_CDP  816
// ---- ws byte offsets ----
#define BIAS_OFF  1024
#define WPOOL_OFF 5120
#define BUF_OFF   1261568          // 4K aligned, past weight pool
#define FEAT_BYTES 18874368        // 4*64*36864*2

// ---- dcn LDS geometry ----
#define WROWS 12
#define WCOLS 12
#define WSTR  72     // elems per window pixel (64ch + 8 pad) = 144 B (odd 16B chunks, aligned)
#define SSTR2 152    // elems per px in s_samp (18 slots*8 + 8 pad) = 304 B (odd 16B chunks)

__device__ __forceinline__ float b2f(bf16 v){ return __bfloat162float(v); }
__device__ __forceinline__ bf16  f2b(float v){ return __float2bfloat16(v); }
__device__ __forceinline__ float us2f(unsigned short u){ return __uint_as_float(((unsigned)u) << 16); }
__device__ __forceinline__ float ld(const void* p, size_t i, int f32){
    if (f32) return ((const float*)p)[i];
    return b2f(((const bf16*)p)[i]);
}

union B8 { uint2 u2[2]; uint4 u4; short8 s8; };
union V8 { uint4 u4; unsigned short us[8]; bf16 h[8]; };

struct P20 { const void* p[20]; int n[20]; };

// ---------------------------------------------------------------------------
// Dtype probe (established: inputs fp32-in-memory, bf16-valued)
// ---------------------------------------------------------------------------
__global__ void detect_kernel(P20 a, int* __restrict__ flags){
    int t = threadIdx.x;
    if (t >= 20) return;
    const unsigned short* u = (const unsigned short*)a.p[t];
    int n = a.n[t]; if (n > 512) n = 512;
    int f32 = 0;
    for (int i = 0; i < n; ++i){
        float v = __uint_as_float(((unsigned)u[i]) << 16);
        if (!(fabsf(v) < 1e3f)) f32 = 1;
    }
    flags[t] = f32;
}

// ---------------------------------------------------------------------------
// Prep: 3x3 conv weights -> bf16 MFMA A-frag layout, tap-major K.
// ---------------------------------------------------------------------------
__global__ void prep_convA(const void* __restrict__ src, const int* __restrict__ flags,
                           int fi, bf16* __restrict__ dst, int Cin, int CoutReal, int OCB)
{
    int idx = blockIdx.x*256 + threadIdx.x;
    int KK = Cin >> 4;
    int total = OCB*9*KK*512;
    if (idx >= total) return;
    int j  = idx & 7;
    int ko = (idx>>3) & 1;
    int m  = (idx>>4) & 31;
    int rest = idx >> 9;
    int kk = rest % KK; rest /= KK;
    int tap = rest % 9;
    int ocb = rest / 9;
    int oc = ocb*32 + m;
    int ci = kk*16 + ko*8 + j;
    float v = 0.f;
    if (oc < CoutReal) v = ld(src, ((size_t)oc*Cin + ci)*9 + tap, flags[fi]);
    dst[idx] = f2b(v);
}

// ---------------------------------------------------------------------------
// Prep: DCN projection weights -> A-frag layout with PERMUTED K:
//   k' = (dg*9 + tap)*8 + cg   (cg contiguous -> vector LDS sample slots)
//   original k = (dg*8 + cg)*9 + tap
// ---------------------------------------------------------------------------
__global__ void prep_projA(const void* __restrict__ src, const int* __restrict__ flags,
                           int fi, bf16* __restrict__ dst)
{
    int idx = blockIdx.x*256 + threadIdx.x;
    if (idx >= 2*36*512) return;
    int j  = idx & 7;
    int ko = (idx>>3) & 1;
    int m  = (idx>>4) & 31;
    int rest = idx >> 9;
    int kk = rest % 36;
    int ocb = rest / 36;
    int oc = ocb*32 + m;
    int kp   = kk*16 + ko*8 + j;   // permuted K index
    int slot = kp >> 3;            // dg*9+tap
    int cg   = kp & 7;
    int dg   = slot / 9;
    int tap  = slot - dg*9;
    int k    = (dg*8 + cg)*9 + tap;
    dst[idx] = f2b(ld(src, (size_t)oc*576 + k, flags[fi]));
}

// ---------------------------------------------------------------------------
// Prep: biases -> fp32 pool
// ---------------------------------------------------------------------------
__global__ void prep_bias(P20 a, const int* __restrict__ flags, float* __restrict__ bp){
    int t = threadIdx.x;
    const int src[9] = {3,5,11,13,15,7,17,9,19};
    const int off[9] = {B_OC1,B_OC2,B_FC,B_CAS1,B_CAS2,B_D1O,B_CDO,B_D1P,B_CDP};
    const int sz[9]  = {64,64,64,64,64,216,216,64,64};
    for (int s = 0; s < 9; ++s)
        if (t < sz[s]) bp[off[s] + t] = ld(a.p[src[s]], t, flags[src[s]]);
}

// ---------------------------------------------------------------------------
// Pack: x [B][64][HW] (fp32 or bf16) -> xi [B][HW][64] bf16 (channel-interleaved)
// Tiled transpose: 64px x 64ch per block, LDS staged, vectorized loads.
// ---------------------------------------------------------------------------
__global__ __launch_bounds__(256)
void pack_x(const void* __restrict__ src, const int* __restrict__ flags, int fi,
            bf16* __restrict__ dst)
{
    __shared__ bf16 s[64*65];            // [ci][px], pad 65 breaks bank stride
    const int b    = blockIdx.y;
    const int pix0 = blockIdx.x * 64;
    const int t    = threadIdx.x;
    const int f    = (fi >= 0) ? flags[fi] : 0;

    const int px8 = (t & 7) * 8;
    const int ci0 = t >> 3;              // 0..31
#pragma unroll
    for (int it = 0; it < 2; ++it){
        int ci = ci0 + it*32;
        size_t g = ((size_t)b*NF + ci)*HWn + pix0 + px8;
        if (f){
            float4 a0 = *(const float4*)((const float*)src + g);
            float4 a1 = *(const float4*)((const float*)src + g + 4);
            bf16* sp = &s[ci*65 + px8];
            sp[0]=f2b(a0.x); sp[1]=f2b(a0.y); sp[2]=f2b(a0.z); sp[3]=f2b(a0.w);
            sp[4]=f2b(a1.x); sp[5]=f2b(a1.y); sp[6]=f2b(a1.z); sp[7]=f2b(a1.w);
        } else {
            V8 v; v.u4 = *(const uint4*)((const bf16*)src + g);
            bf16* sp = &s[ci*65 + px8];
#pragma unroll
            for (int j = 0; j < 8; ++j) sp[j] = v.h[j];
        }
    }
    __syncthreads();

    const int px  = t >> 2;
    const int ch0 = (t & 3) * 16;
    V8 o0, o1;
#pragma unroll
    for (int j = 0; j < 8; ++j){
        o0.h[j] = s[(ch0 + j)*65 + px];
        o1.h[j] = s[(ch0 + 8 + j)*65 + px];
    }
    bf16* dp = dst + ((size_t)b*HWn + pix0 + px)*64 + ch0;
    *(uint4*)(dp)     = o0.u4;
    *(uint4*)(dp + 8) = o1.u4;
}

// ---------------------------------------------------------------------------
// MFMA implicit-GEMM 3x3 conv (pad=1). Block: 256 thr = 4 waves, tile 64oc x 64px.
// ACT: 0=none, 1=lrelu, 2=dcn-offset epilogue (sigmoid for oc>=144, raw below).
// ---------------------------------------------------------------------------
__global__ __launch_bounds__(256)
void conv_mfma(const void* __restrict__ inA, const void* __restrict__ inB,
               const bf16* __restrict__ wA, const float* __restrict__ bias,
               bf16* __restrict__ out,
               int CinA, int CinB, int CoutReal, int OutChStore, int ACT,
               const int* __restrict__ flags, int fiA, int fiB)
{
    extern __shared__ __align__(16) char smem_raw[];
    bf16* s_in = (bf16*)smem_raw;

    const int CinT  = CinA + CinB;
    const int ciPad = CinT + 4;                 // 68 or 132
    const int b     = blockIdx.z;
    const int pix0  = blockIdx.x * 64;          // 64 px, same row (192%64==0)
    const int h     = pix0 / Wn;
    const int x0    = pix0 - h*Wn;
    const int ocBase= blockIdx.y * 64;
    const int tid   = threadIdx.x;
    const int fA = (fiA>=0)?flags[fiA]:0;
    const int fB = (fiB>=0)?flags[fiB]:0;

    // ---- stage patch: rows h-1..h+1, cols x0-1..x0+64, all CinT channels ----
    const int total = 3*66*CinT;
    for (int idx = tid; idx < total; idx += 256){
        int c  = idx % 66;
        int r  = idx / 66;
        int ky = r % 3;
        int ci = r / 3;
        int y  = h - 1 + ky;
        int xx = x0 - 1 + c;
        float v = 0.f;
        if ((unsigned)y < (unsigned)Hn && (unsigned)xx < (unsigned)Wn){
            if (ci < CinA) v = ld(inA, ((size_t)b*CinA + ci)*HWn + y*Wn + xx, fA);
            else           v = ld(inB, ((size_t)b*CinB + (ci-CinA))*HWn + y*Wn + xx, fB);
        }
        s_in[(ky*66 + c)*ciPad + ci] = f2b(v);
    }
    __syncthreads();

    // ---- MFMA main loop ----
    const int w    = tid >> 6;
    const int lane = tid & 63;
    const int m    = lane & 31;
    const int half = lane >> 5;
    const int och  = (w >> 1) * 32;
    const int pxh  = (w & 1) * 32;
    const int KK   = CinT >> 4;
    const int ocb  = blockIdx.y*2 + (w >> 1);

    floatx16 acc;
#pragma unroll
    for (int r = 0; r < 16; ++r) acc[r] = 0.f;

    const bf16* wAb = wA + ((size_t)ocb*9*KK)*512 + m*16 + half*8;
    const int col0 = pxh + m;

#pragma unroll
    for (int tap = 0; tap < 9; ++tap){
        const int ky = tap/3, kx = tap - (tap/3)*3;
        const bf16* srow = s_in + (ky*66 + col0 + kx)*ciPad + half*8;
        for (int kk = 0; kk < KK; ++kk){
            B8 ba; ba.u4 = *(const uint4*)(wAb + (size_t)(tap*KK + kk)*512);
            B8 bb;
            const bf16* sp = srow + kk*16;
            bb.u2[0] = *(const uint2*)(sp);
            bb.u2[1] = *(const uint2*)(sp + 4);
            acc = __builtin_amdgcn_mfma_f32_32x32x16_bf16(ba.s8, bb.s8, acc, 0, 0, 0);
        }
    }

    // ---- epilogue ----
    const int pxo = pix0 + pxh + m;
#pragma unroll
    for (int r = 0; r < 16; ++r){
        int row = (r & 3) + 8*(r >> 2) + 4*half;
        int oc  = ocBase + och + row;
        if (oc < CoutReal){
            float v = acc[r] + bias[oc];
            if (ACT == 1) v = (v >= 0.f) ? v : 0.1f*v;
            else if (ACT == 2 && oc >= 144) v = 1.f/(1.f + expf(-v));  // mask sigmoid
            out[((size_t)b*OutChStore + oc)*HWn + pxo] = f2b(v);
        }
    }
}

// ---------------------------------------------------------------------------
// DCN sample + MFMA projection, LDS-WINDOW GATHER version.
// Block: 256 thr, 8x8 px tile. Theory: the gathers were bound by per-CU
// L1-miss/line-request throughput (rounds 1-3: time invariant to gather
// instr count AND to occupancy). Fix: stage the 12x12-px support window
// (20.7 KB) into LDS coalesced, gather bilinear corners from LDS (ds pipe,
// no TA/L1 involvement). Rare out-of-window samples fall back to global
// (execz-skipped). s_samp split into 4 K-passes (18 slots, 19.5 KB) so
// window+samp = 40.2 KB -> 4 blocks/CU. launch_bounds(256,2): VGPR cap 128
// (NOT (256,4): that caps arch VGPRs at 64 and spills -- round-3 lesson).
// ---------------------------------------------------------------------------
__global__ __launch_bounds__(256, 2)
void dcn_mfma(const bf16* __restrict__ xi,     // interleaved [B][HW][64] bf16
              const bf16* __restrict__ offs,   // [B][216][HW] bf16 (masks sigmoided)
              const bf16* __restrict__ wP,     // A-frag layout, K permuted
              const float* __restrict__ pbias, // [64]
              void* __restrict__ out, int outF32, int ACT)
{
    __shared__ __align__(16) bf16 s_win[WROWS*WCOLS*WSTR];   // 20,736 B
    __shared__ __align__(16) bf16 s_samp[64*SSTR2];          // 19,456 B

    const int b   = blockIdx.y;
    const int bx  = blockIdx.x;
    const int tx  = bx % (Wn/8);
    const int ty  = bx / (Wn/8);
    const int gx0 = tx*8, gy0 = ty*8;
    const int wx0 = gx0 - 2, wy0 = gy0 - 2;
    const int tid = threadIdx.x;

    const bf16* xb = xi + (size_t)b*HWn*64;

    // ---- stage window: 144 px x 64 ch, coalesced dwordx4, zero OOB ----
    for (int c = tid; c < WROWS*WCOLS*8; c += 256){
        int ch4 = c & 7;
        int pxi = c >> 3;
        int gy  = wy0 + pxi/WCOLS;
        int gx  = wx0 + pxi%WCOLS;
        uint4 v = {0u,0u,0u,0u};
        if ((unsigned)gy < (unsigned)Hn && (unsigned)gx < (unsigned)Wn)
            v = *(const uint4*)(xb + ((size_t)gy*Wn + gx)*64 + ch4*8);
        *(uint4*)&s_win[pxi*WSTR + ch4*8] = v;
    }

    const int px   = tid & 63;          // this thread's sample pixel
    const int wq   = tid >> 6;
    const int pr   = px >> 3, pc = px & 7;
    const int gy   = gy0 + pr, gx = gx0 + pc;
    const int m    = px & 31;
    const int half = px >> 5;
    const int och  = (wq >> 1) * 32;
    const int pxh  = (wq & 1) * 32;

    const size_t obase = (size_t)b*216*HWn + (size_t)gy*Wn + gx;
    const uint4 z4 = {0u,0u,0u,0u};

    const bf16* wPb  = wP + ((size_t)(wq>>1)*36)*512 + m*16 + half*8;
    const bf16* srow = s_samp + (pxh + m)*SSTR2 + half*8;

    floatx16 acc;
#pragma unroll
    for (int r = 0; r < 16; ++r) acc[r] = 0.f;

    for (int pass = 0; pass < 4; ++pass){
        __syncthreads();   // pass 0: window staged; else: prev Phase D done

        // ---- Phase C: sample slots sl = wq, wq+4, ... < 18 for this pass ----
#pragma unroll
        for (int ii = 0; ii < 5; ++ii){
            int sl = wq + ii*4;
            if (sl < 18){
                int dgl = sl / 9;
                int tap = sl - dgl*9;
                int dg  = pass*2 + dgl;
                int ky  = tap / 3;
                int kx  = tap - ky*3;
                float dy = b2f(offs[obase + (size_t)(dg*18 + tap*2    )*HWn]);
                float dx = b2f(offs[obase + (size_t)(dg*18 + tap*2 + 1)*HWn]);
                float mk = b2f(offs[obase + (size_t)(144 + dg*9 + tap )*HWn]);
                float py  = dy + (float)(gy - 1 + ky);
                float pxx = dx + (float)(gx - 1 + kx);
                float y0f = floorf(py), x0f = floorf(pxx);
                int   y0  = (int)y0f,   xi0 = (int)x0f;
                float wy  = py - y0f,   wx  = pxx - x0f;
                float w00 = (1.f-wy)*(1.f-wx)*mk, w01 = (1.f-wy)*wx*mk;
                float w10 = wy*(1.f-wx)*mk,       w11 = wy*wx*mk;
                int ly = y0 - wy0, lx = xi0 - wx0;

                auto fetch = [&](int ly_, int lx_, int y_, int x_) -> uint4 {
                    if ((unsigned)ly_ < (unsigned)WROWS && (unsigned)lx_ < (unsigned)WCOLS)
                        return *(const uint4*)&s_win[(ly_*WCOLS + lx_)*WSTR + dg*8];
                    if ((unsigned)y_ < (unsigned)Hn && (unsigned)x_ < (unsigned)Wn)
                        return *(const uint4*)(xb + ((size_t)y_*Wn + x_)*64 + dg*8);
                    return z4;
                };
                V8 c00, c01, c10, c11, o;
                c00.u4 = fetch(ly,   lx,   y0,   xi0  );
                c01.u4 = fetch(ly,   lx+1, y0,   xi0+1);
                c10.u4 = fetch(ly+1, lx,   y0+1, xi0  );
                c11.u4 = fetch(ly+1, lx+1, y0+1, xi0+1);
#pragma unroll
                for (int j = 0; j < 8; ++j){
                    float v = w00*us2f(c00.us[j]) + w01*us2f(c01.us[j])
                            + w10*us2f(c10.us[j]) + w11*us2f(c11.us[j]);
                    o.h[j] = f2b(v);
                }
                *(uint4*)&s_samp[px*SSTR2 + sl*8] = o.u4;
            }
        }
        __syncthreads();

        // ---- Phase D: 9 MFMAs over this pass's 144 K-elems ----
#pragma unroll
        for (int kk = 0; kk < 9; ++kk){
            B8 ba; ba.u4 = *(const uint4*)(wPb + (size_t)(pass*9 + kk)*512);
            B8 bb; bb.u4 = *(const uint4*)(srow + kk*16);
            acc = __builtin_amdgcn_mfma_f32_32x32x16_bf16(ba.s8, bb.s8, acc, 0, 0, 0);
        }
    }

    // ---- epilogue ----
    const int opx = pxh + m;
    const int pxo = (gy0 + (opx >> 3))*Wn + gx0 + (opx & 7);
#pragma unroll
    for (int r = 0; r < 16; ++r){
        int row = (r & 3) + 8*(r >> 2) + 4*half;
        int oc  = och + row;
        float v = acc[r] + pbias[oc];
        if (ACT) v = (v >= 0.f) ? v : 0.1f*v;
        size_t oi = ((size_t)b*NF + oc)*HWn + pxo;
        if (outF32) ((float*)out)[oi] = v;
        else        ((bf16*) out)[oi] = f2b(v);
    }
}

// ---------------------------------------------------------------------------
extern "C" void kernel_launch(void* const* d_in, const int* in_sizes, int n_in,
                              void* d_out, int out_size, void* d_ws, size_t ws_size,
                              hipStream_t stream)
{
    enum { I_NBR=0, I_REF=1, I_OC1W=2, I_OC2W=4, I_D1OW=6, I_D1W=8, I_FCW=10,
           I_C1W=12, I_C2W=14, I_CDOW=16, I_CDW=18 };

    int*   flags = (int*)d_ws;
    float* bp    = (float*)((char*)d_ws + BIAS_OFF);
    bf16*  wp    = (bf16*) ((char*)d_ws + WPOOL_OFF);
    bf16*  t1    = (bf16*) ((char*)d_ws + BUF_OFF);
    bf16*  f1    = (bf16*) ((char*)d_ws + BUF_OFF + FEAT_BYTES);
    bf16*  offs  = (bf16*) ((char*)d_ws + BUF_OFF + 2*(size_t)FEAT_BYTES);
    bf16*  t0    = (bf16*) d_out;   // fp32-sized out doubles as bf16 scratch
    bf16*  nbr_i = (bf16*)((char*)d_out + FEAT_BYTES);  // second half of d_out
    bf16*  f1i   = t1;              // t1 region dead after step 8

    P20 a;
    for (int i = 0; i < 20; ++i){ a.p[i] = d_in[i]; a.n[i] = in_sizes[i]; }

    detect_kernel<<<1, 64, 0, stream>>>(a, flags);
    prep_bias<<<1, 256, 0, stream>>>(a, flags, bp);
    prep_convA<<<288, 256, 0, stream>>>(d_in[I_OC1W], flags, I_OC1W, wp+WA_OC1, 128, 64, 2);
    prep_convA<<<144, 256, 0, stream>>>(d_in[I_OC2W], flags, I_OC2W, wp+WA_OC2,  64, 64, 2);
    prep_convA<<<144, 256, 0, stream>>>(d_in[I_FCW],  flags, I_FCW,  wp+WA_FC,   64, 64, 2);
    prep_convA<<<288, 256, 0, stream>>>(d_in[I_C1W],  flags, I_C1W,  wp+WA_CAS1,128, 64, 2);
    prep_convA<<<144, 256, 0, stream>>>(d_in[I_C2W],  flags, I_C2W,  wp+WA_CAS2, 64, 64, 2);
    prep_convA<<<576, 256, 0, stream>>>(d_in[I_D1OW], flags, I_D1OW, wp+WA_D1O,  64, 216, 8);
    prep_convA<<<576, 256, 0, stream>>>(d_in[I_CDOW], flags, I_CDOW, wp+WA_CDO,  64, 216, 8);
    prep_projA<<<144, 256, 0, stream>>>(d_in[I_D1W],  flags, I_D1W,  wp+WP_D1);
    prep_projA<<<144, 256, 0, stream>>>(d_in[I_CDW],  flags, I_CDW,  wp+WP_CD);

    dim3 blk(256,1,1);
    const int smem64  = 3*66*68*2;    // 26928 B
    const int smem128 = 3*66*132*2;   // 52272 B
    dim3 g64 (576, 1, Bn);
    dim3 g216(576, 4, Bn);
    dim3 gD  (576, Bn, 1);            // 24x24 8x8-px tiles
    dim3 gP  (576, Bn, 1);

    // 0. nbr_i = pack(nbr) channel-interleaved bf16 (lives in d_out 2nd half)
    pack_x<<<gP, blk, 0, stream>>>(d_in[I_NBR], flags, I_NBR, nbr_i);
    // 1. t0 = lrelu(conv(cat(nbr,ref), oc1))
    conv_mfma<<<g64, blk, smem128, stream>>>(d_in[I_NBR], d_in[I_REF], wp+WA_OC1, bp+B_OC1,
        t0, 64, 64, 64, 64, 1, flags, I_NBR, I_REF);
    // 2. t1 = lrelu(conv(t0, oc2))
    conv_mfma<<<g64, blk, smem64, stream>>>(t0, nullptr, wp+WA_OC2, bp+B_OC2,
        t1, 64, 0, 64, 64, 1, flags, -1, -1);
    // 3. offs = conv(t1, d1o)  [offsets raw, masks sigmoided via ACT=2]
    conv_mfma<<<g216, blk, smem64, stream>>>(t1, nullptr, wp+WA_D1O, bp+B_D1O,
        offs, 64, 0, 216, 216, 2, flags, -1, -1);
    // 4. t1 = dcn(x=nbr_i, offs; proj d1)
    dcn_mfma<<<gD, blk, 0, stream>>>(nbr_i, offs, wp+WP_D1, bp+B_D1P,
        t1, 0, 0);
    // 5. f1 = conv(t1, fc)  (no act)
    conv_mfma<<<g64, blk, smem64, stream>>>(t1, nullptr, wp+WA_FC, bp+B_FC,
        f1, 64, 0, 64, 64, 0, flags, -1, -1);
    // 6. t0 = lrelu(conv(cat(f1, ref), cas1))
    conv_mfma<<<g64, blk, smem128, stream>>>(f1, d_in[I_REF], wp+WA_CAS1, bp+B_CAS1,
        t0, 64, 64, 64, 64, 1, flags, -1, I_REF);
    // 7. t1 = lrelu(conv(t0, cas2))
    conv_mfma<<<g64, blk, smem64, stream>>>(t0, nullptr, wp+WA_CAS2, bp+B_CAS2,
        t1, 64, 0, 64, 64, 1, flags, -1, -1);
    // 8. offs = conv(t1, cdo)  [ACT=2]
    conv_mfma<<<g216, blk, smem64, stream>>>(t1, nullptr, wp+WA_CDO, bp+B_CDO,
        offs, 64, 0, 216, 216, 2, flags, -1, -1);
    // 8b. f1i = pack(f1) channel-interleaved (into t1 region, dead after step 8)
    pack_x<<<gP, blk, 0, stream>>>(f1, flags, -1, f1i);
    // 9. d_out = lrelu(dcn(x=f1i, offs; proj cd))  fp32
    dcn_mfma<<<gD, blk, 0, stream>>>(f1i, offs, wp+WP_CD, bp+B_CDP,
        d_out, 1, 1);
}

// Round 6
// 893.718 us; speedup vs baseline: 2.9252x; 1.7423x over previous
//
#include <hip/hip_runtime.h>
#include <hip/hip_bf16.h>
#include <math.h>

typedef __hip_bfloat16 bf16;
typedef float  floatx16 __attribute__((ext_vector_type(16)));
typedef short  short8   __attribute__((ext_vector_type(8)));

#define Bn 4
#define NF 64
#define Hn 192
#define Wn 192
#define HWn (Hn*Wn)

// ---- weight pool element offsets (bf16 elements, relative to WPOOL) ----
#define WA_OC1  0
#define WA_OC2  73728
#define WA_FC   110592
#define WA_CAS1 147456
#define WA_CAS2 221184
#define WA_D1O  258048
#define WA_CDO  405504
#define WP_D1   552960
#define WP_CD   589824
// ---- bias pool float offsets ----
#define B_OC1  0
#define B_OC2  64
#define B_FC   128
#define B_CAS1 192
#define B_CAS2 256
#define B_D1O  320
#define B_CDO  536
#define B_D1P  752
#define B_CDP  816
// ---- ws byte offsets ----
#define BIAS_OFF  1024
#define WPOOL_OFF 5120
#define BUF_OFF   1261568          // 4K aligned, past weight pool
#define FEAT_BYTES 18874368        // 4*64*36864*2

// ---- dcn LDS geometry ----
#define WROWS 12
#define WCOLS 12
#define WSTR  72     // elems per window pixel (64ch + 8 pad) = 144 B (odd 16B chunks, aligned)
#define SSTR2 152    // elems per px in s_samp (18 slots*8 + 8 pad) = 304 B (odd 16B chunks)

__device__ __forceinline__ float b2f(bf16 v){ return __bfloat162float(v); }
__device__ __forceinline__ bf16  f2b(float v){ return __float2bfloat16(v); }
__device__ __forceinline__ float us2f(unsigned short u){ return __uint_as_float(((unsigned)u) << 16); }
__device__ __forceinline__ float ld(const void* p, size_t i, int f32){
    if (f32) return ((const float*)p)[i];
    return b2f(((const bf16*)p)[i]);
}

union B8 { uint2 u2[2]; uint4 u4; short8 s8; };
union V8 { uint4 u4; unsigned short us[8]; bf16 h[8]; };
union V4 { uint2 u2; bf16 h[4]; };

struct P20 { const void* p[20]; int n[20]; };

// ---------------------------------------------------------------------------
// Dtype probe (established: inputs fp32-in-memory, bf16-valued)
// ---------------------------------------------------------------------------
__global__ void detect_kernel(P20 a, int* __restrict__ flags){
    int t = threadIdx.x;
    if (t >= 20) return;
    const unsigned short* u = (const unsigned short*)a.p[t];
    int n = a.n[t]; if (n > 512) n = 512;
    int f32 = 0;
    for (int i = 0; i < n; ++i){
        float v = __uint_as_float(((unsigned)u[i]) << 16);
        if (!(fabsf(v) < 1e3f)) f32 = 1;
    }
    flags[t] = f32;
}

// ---------------------------------------------------------------------------
// Prep: 3x3 conv weights -> bf16 MFMA A-frag layout, tap-major K.
// ---------------------------------------------------------------------------
__global__ void prep_convA(const void* __restrict__ src, const int* __restrict__ flags,
                           int fi, bf16* __restrict__ dst, int Cin, int CoutReal, int OCB)
{
    int idx = blockIdx.x*256 + threadIdx.x;
    int KK = Cin >> 4;
    int total = OCB*9*KK*512;
    if (idx >= total) return;
    int j  = idx & 7;
    int ko = (idx>>3) & 1;
    int m  = (idx>>4) & 31;
    int rest = idx >> 9;
    int kk = rest % KK; rest /= KK;
    int tap = rest % 9;
    int ocb = rest / 9;
    int oc = ocb*32 + m;
    int ci = kk*16 + ko*8 + j;
    float v = 0.f;
    if (oc < CoutReal) v = ld(src, ((size_t)oc*Cin + ci)*9 + tap, flags[fi]);
    dst[idx] = f2b(v);
}

// ---------------------------------------------------------------------------
// Prep: DCN projection weights -> A-frag layout with PERMUTED K:
//   k' = (dg*9 + tap)*8 + cg ; original k = (dg*8 + cg)*9 + tap
// ---------------------------------------------------------------------------
__global__ void prep_projA(const void* __restrict__ src, const int* __restrict__ flags,
                           int fi, bf16* __restrict__ dst)
{
    int idx = blockIdx.x*256 + threadIdx.x;
    if (idx >= 2*36*512) return;
    int j  = idx & 7;
    int ko = (idx>>3) & 1;
    int m  = (idx>>4) & 31;
    int rest = idx >> 9;
    int kk = rest % 36;
    int ocb = rest / 36;
    int oc = ocb*32 + m;
    int kp   = kk*16 + ko*8 + j;
    int slot = kp >> 3;
    int cg   = kp & 7;
    int dg   = slot / 9;
    int tap  = slot - dg*9;
    int k    = (dg*8 + cg)*9 + tap;
    dst[idx] = f2b(ld(src, (size_t)oc*576 + k, flags[fi]));
}

// ---------------------------------------------------------------------------
// Prep: biases -> fp32 pool
// ---------------------------------------------------------------------------
__global__ void prep_bias(P20 a, const int* __restrict__ flags, float* __restrict__ bp){
    int t = threadIdx.x;
    const int src[9] = {3,5,11,13,15,7,17,9,19};
    const int off[9] = {B_OC1,B_OC2,B_FC,B_CAS1,B_CAS2,B_D1O,B_CDO,B_D1P,B_CDP};
    const int sz[9]  = {64,64,64,64,64,216,216,64,64};
    for (int s = 0; s < 9; ++s)
        if (t < sz[s]) bp[off[s] + t] = ld(a.p[src[s]], t, flags[src[s]]);
}

// ---------------------------------------------------------------------------
// Pack: x [B][64][HW] (fp32 or bf16) -> NHWC [B][HW][64] bf16
// ---------------------------------------------------------------------------
__global__ __launch_bounds__(256)
void pack_x(const void* __restrict__ src, const int* __restrict__ flags, int fi,
            bf16* __restrict__ dst)
{
    __shared__ bf16 s[64*65];
    const int b    = blockIdx.y;
    const int pix0 = blockIdx.x * 64;
    const int t    = threadIdx.x;
    const int f    = (fi >= 0) ? flags[fi] : 0;

    const int px8 = (t & 7) * 8;
    const int ci0 = t >> 3;
#pragma unroll
    for (int it = 0; it < 2; ++it){
        int ci = ci0 + it*32;
        size_t g = ((size_t)b*NF + ci)*HWn + pix0 + px8;
        if (f){
            float4 a0 = *(const float4*)((const float*)src + g);
            float4 a1 = *(const float4*)((const float*)src + g + 4);
            bf16* sp = &s[ci*65 + px8];
            sp[0]=f2b(a0.x); sp[1]=f2b(a0.y); sp[2]=f2b(a0.z); sp[3]=f2b(a0.w);
            sp[4]=f2b(a1.x); sp[5]=f2b(a1.y); sp[6]=f2b(a1.z); sp[7]=f2b(a1.w);
        } else {
            V8 v; v.u4 = *(const uint4*)((const bf16*)src + g);
            bf16* sp = &s[ci*65 + px8];
#pragma unroll
            for (int j = 0; j < 8; ++j) sp[j] = v.h[j];
        }
    }
    __syncthreads();

    const int px  = t >> 2;
    const int ch0 = (t & 3) * 16;
    V8 o0, o1;
#pragma unroll
    for (int j = 0; j < 8; ++j){
        o0.h[j] = s[(ch0 + j)*65 + px];
        o1.h[j] = s[(ch0 + 8 + j)*65 + px];
    }
    bf16* dp = dst + ((size_t)b*HWn + pix0 + px)*64 + ch0;
    *(uint4*)(dp)     = o0.u4;
    *(uint4*)(dp + 8) = o1.u4;
}

// ---------------------------------------------------------------------------
// MFMA implicit-GEMM 3x3 conv, NHWC bf16 inputs. Block: 256 thr, 64px tile.
// Staging = linear uint4 copies (no transpose, no div, no f2b).
// nOcb: oc-tile loop (1 for 64-out, 4 for 216-out) reusing the staged patch.
// ACT: 0=none(NHWC out) 1=lrelu(NHWC out) 2=offs epilogue (NCHW out, sigmoid oc>=144).
// ---------------------------------------------------------------------------
__global__ __launch_bounds__(256)
void conv_mfma(const bf16* __restrict__ inA, const bf16* __restrict__ inB,
               const bf16* __restrict__ wA, const float* __restrict__ bias,
               bf16* __restrict__ out,
               int nOcb, int CoutReal, int OutChStore, int ACT)
{
    extern __shared__ __align__(16) char smem_raw[];
    bf16* s_in = (bf16*)smem_raw;

    const int CinT  = inB ? 128 : 64;
    const int ciPad = CinT + 4;                 // 68 or 132 (2-way-free b64 reads)
    const int b     = blockIdx.z;
    const int pix0  = blockIdx.x * 64;          // 64 px, same row (192%64==0)
    const int h     = pix0 / Wn;
    const int x0    = pix0 - h*Wn;
    const int tid   = threadIdx.x;

    // ---- stage patch: 3 rows x 66 px x CinT ch, pure vector copies ----
    for (int ky = 0; ky < 3; ++ky){
        const int y  = h - 1 + ky;
        const bool yv = (unsigned)y < (unsigned)Hn;
        const size_t rb = ((size_t)b*HWn + (size_t)y*Wn)*64;
        for (int e = tid; e < 528; e += 256){
            const int c = e >> 3, ch8 = e & 7;
            const int x = x0 - 1 + c;
            const bool v = yv && (unsigned)x < (unsigned)Wn;
            B8 va; va.u4 = make_uint4(0,0,0,0);
            if (v) va.u4 = *(const uint4*)(inA + rb + (size_t)x*64 + ch8*8);
            bf16* dp = &s_in[(ky*66 + c)*ciPad + ch8*8];
            *(uint2*)(dp)     = va.u2[0];
            *(uint2*)(dp + 4) = va.u2[1];
            if (inB){
                B8 vb; vb.u4 = make_uint4(0,0,0,0);
                if (v) vb.u4 = *(const uint4*)(inB + rb + (size_t)x*64 + ch8*8);
                bf16* dq = dp + 64;
                *(uint2*)(dq)     = vb.u2[0];
                *(uint2*)(dq + 4) = vb.u2[1];
            }
        }
    }
    __syncthreads();

    // ---- MFMA + epilogue, looped over oc-tiles ----
    const int w    = tid >> 6;
    const int lane = tid & 63;
    const int m    = lane & 31;
    const int half = lane >> 5;
    const int och  = (w >> 1) * 32;
    const int pxh  = (w & 1) * 32;
    const int KK   = CinT >> 4;
    const int col0 = pxh + m;
    const int pxo  = pix0 + pxh + m;

    for (int ot = 0; ot < nOcb; ++ot){
        const int ocb = ot*2 + (w >> 1);
        floatx16 acc;
#pragma unroll
        for (int r = 0; r < 16; ++r) acc[r] = 0.f;

        const bf16* wAb = wA + ((size_t)ocb*9*KK)*512 + m*16 + half*8;
#pragma unroll
        for (int tap = 0; tap < 9; ++tap){
            const int ky = tap/3, kx = tap - (tap/3)*3;
            const bf16* srow = s_in + (ky*66 + col0 + kx)*ciPad + half*8;
            for (int kk = 0; kk < KK; ++kk){
                B8 ba; ba.u4 = *(const uint4*)(wAb + (size_t)(tap*KK + kk)*512);
                B8 bb;
                const bf16* sp = srow + kk*16;
                bb.u2[0] = *(const uint2*)(sp);
                bb.u2[1] = *(const uint2*)(sp + 4);
                acc = __builtin_amdgcn_mfma_f32_32x32x16_bf16(ba.s8, bb.s8, acc, 0, 0, 0);
            }
        }

        if (ACT == 2){
            // NCHW offs output + mask sigmoid
#pragma unroll
            for (int r = 0; r < 16; ++r){
                int row = (r & 3) + 8*(r >> 2) + 4*half;
                int oc  = ot*64 + och + row;
                if (oc < CoutReal){
                    float v = acc[r] + bias[oc];
                    if (oc >= 144) v = 1.f/(1.f + expf(-v));
                    out[((size_t)b*OutChStore + oc)*HWn + pxo] = f2b(v);
                }
            }
        } else {
            // NHWC 64-ch output: 4 x 8B stores per lane
            bf16* ob = out + ((size_t)b*HWn + pxo)*64 + och + 4*half;
#pragma unroll
            for (int q = 0; q < 4; ++q){
                V4 u;
#pragma unroll
                for (int j = 0; j < 4; ++j){
                    int oc = och + 4*half + 8*q + j;
                    float v = acc[q*4 + j] + bias[oc];
                    if (ACT == 1) v = (v >= 0.f) ? v : 0.1f*v;
                    u.h[j] = f2b(v);
                }
                *(uint2*)(ob + 8*q) = u.u2;
            }
        }
    }
}

// ---------------------------------------------------------------------------
// DCN sample + MFMA projection, LDS-WINDOW GATHER (proven round 5).
// outF32=1 -> NCHW fp32 (final); outF32=0 -> NHWC bf16 (feeds next conv).
// ---------------------------------------------------------------------------
__global__ __launch_bounds__(256, 2)
void dcn_mfma(const bf16* __restrict__ xi,     // NHWC [B][HW][64] bf16
              const bf16* __restrict__ offs,   // NCHW [B][216][HW] bf16 (masks sigmoided)
              const bf16* __restrict__ wP,     // A-frag layout, K permuted
              const float* __restrict__ pbias, // [64]
              void* __restrict__ out, int outF32, int ACT)
{
    __shared__ __align__(16) bf16 s_win[WROWS*WCOLS*WSTR];   // 20,736 B
    __shared__ __align__(16) bf16 s_samp[64*SSTR2];          // 19,456 B

    const int b   = blockIdx.y;
    const int bx  = blockIdx.x;
    const int tx  = bx % (Wn/8);
    const int ty  = bx / (Wn/8);
    const int gx0 = tx*8, gy0 = ty*8;
    const int wx0 = gx0 - 2, wy0 = gy0 - 2;
    const int tid = threadIdx.x;

    const bf16* xb = xi + (size_t)b*HWn*64;

    // ---- stage window: 144 px x 64 ch, coalesced dwordx4, zero OOB ----
    for (int c = tid; c < WROWS*WCOLS*8; c += 256){
        int ch4 = c & 7;
        int pxi = c >> 3;
        int gy  = wy0 + pxi/WCOLS;
        int gx  = wx0 + pxi%WCOLS;
        uint4 v = {0u,0u,0u,0u};
        if ((unsigned)gy < (unsigned)Hn && (unsigned)gx < (unsigned)Wn)
            v = *(const uint4*)(xb + ((size_t)gy*Wn + gx)*64 + ch4*8);
        *(uint4*)&s_win[pxi*WSTR + ch4*8] = v;
    }

    const int px   = tid & 63;
    const int wq   = tid >> 6;
    const int pr   = px >> 3, pc = px & 7;
    const int gy   = gy0 + pr, gx = gx0 + pc;
    const int m    = px & 31;
    const int half = px >> 5;
    const int och  = (wq >> 1) * 32;
    const int pxh  = (wq & 1) * 32;

    const size_t obase = (size_t)b*216*HWn + (size_t)gy*Wn + gx;
    const uint4 z4 = {0u,0u,0u,0u};

    const bf16* wPb  = wP + ((size_t)(wq>>1)*36)*512 + m*16 + half*8;
    const bf16* srow = s_samp + (pxh + m)*SSTR2 + half*8;

    floatx16 acc;
#pragma unroll
    for (int r = 0; r < 16; ++r) acc[r] = 0.f;

    for (int pass = 0; pass < 4; ++pass){
        __syncthreads();

#pragma unroll
        for (int ii = 0; ii < 5; ++ii){
            int sl = wq + ii*4;
            if (sl < 18){
                int dgl = sl / 9;
                int tap = sl - dgl*9;
                int dg  = pass*2 + dgl;
                int ky  = tap / 3;
                int kx  = tap - ky*3;
                float dy = b2f(offs[obase + (size_t)(dg*18 + tap*2    )*HWn]);
                float dx = b2f(offs[obase + (size_t)(dg*18 + tap*2 + 1)*HWn]);
                float mk = b2f(offs[obase + (size_t)(144 + dg*9 + tap )*HWn]);
                float py  = dy + (float)(gy - 1 + ky);
                float pxx = dx + (float)(gx - 1 + kx);
                float y0f = floorf(py), x0f = floorf(pxx);
                int   y0  = (int)y0f,   xi0 = (int)x0f;
                float wy  = py - y0f,   wx  = pxx - x0f;
                float w00 = (1.f-wy)*(1.f-wx)*mk, w01 = (1.f-wy)*wx*mk;
                float w10 = wy*(1.f-wx)*mk,       w11 = wy*wx*mk;
                int ly = y0 - wy0, lx = xi0 - wx0;

                auto fetch = [&](int ly_, int lx_, int y_, int x_) -> uint4 {
                    if ((unsigned)ly_ < (unsigned)WROWS && (unsigned)lx_ < (unsigned)WCOLS)
                        return *(const uint4*)&s_win[(ly_*WCOLS + lx_)*WSTR + dg*8];
                    if ((unsigned)y_ < (unsigned)Hn && (unsigned)x_ < (unsigned)Wn)
                        return *(const uint4*)(xb + ((size_t)y_*Wn + x_)*64 + dg*8);
                    return z4;
                };
                V8 c00, c01, c10, c11, o;
                c00.u4 = fetch(ly,   lx,   y0,   xi0  );
                c01.u4 = fetch(ly,   lx+1, y0,   xi0+1);
                c10.u4 = fetch(ly+1, lx,   y0+1, xi0  );
                c11.u4 = fetch(ly+1, lx+1, y0+1, xi0+1);
#pragma unroll
                for (int j = 0; j < 8; ++j){
                    float v = w00*us2f(c00.us[j]) + w01*us2f(c01.us[j])
                            + w10*us2f(c10.us[j]) + w11*us2f(c11.us[j]);
                    o.h[j] = f2b(v);
                }
                *(uint4*)&s_samp[px*SSTR2 + sl*8] = o.u4;
            }
        }
        __syncthreads();

#pragma unroll
        for (int kk = 0; kk < 9; ++kk){
            B8 ba; ba.u4 = *(const uint4*)(wPb + (size_t)(pass*9 + kk)*512);
            B8 bb; bb.u4 = *(const uint4*)(srow + kk*16);
            acc = __builtin_amdgcn_mfma_f32_32x32x16_bf16(ba.s8, bb.s8, acc, 0, 0, 0);
        }
    }

    // ---- epilogue ----
    const int opx = pxh + m;
    const int pxo = (gy0 + (opx >> 3))*Wn + gx0 + (opx & 7);
    if (outF32){
#pragma unroll
        for (int r = 0; r < 16; ++r){
            int row = (r & 3) + 8*(r >> 2) + 4*half;
            int oc  = och + row;
            float v = acc[r] + pbias[oc];
            if (ACT) v = (v >= 0.f) ? v : 0.1f*v;
            ((float*)out)[((size_t)b*NF + oc)*HWn + pxo] = v;
        }
    } else {
        bf16* ob = (bf16*)out + ((size_t)b*HWn + pxo)*64 + och + 4*half;
#pragma unroll
        for (int q = 0; q < 4; ++q){
            V4 u;
#pragma unroll
            for (int j = 0; j < 4; ++j){
                int oc = och + 4*half + 8*q + j;
                float v = acc[q*4 + j] + pbias[oc];
                if (ACT) v = (v >= 0.f) ? v : 0.1f*v;
                u.h[j] = f2b(v);
            }
            *(uint2*)(ob + 8*q) = u.u2;
        }
    }
}

// ---------------------------------------------------------------------------
extern "C" void kernel_launch(void* const* d_in, const int* in_sizes, int n_in,
                              void* d_out, int out_size, void* d_ws, size_t ws_size,
                              hipStream_t stream)
{
    enum { I_NBR=0, I_REF=1, I_OC1W=2, I_OC2W=4, I_D1OW=6, I_D1W=8, I_FCW=10,
           I_C1W=12, I_C2W=14, I_CDOW=16, I_CDW=18 };

    int*   flags = (int*)d_ws;
    float* bp    = (float*)((char*)d_ws + BIAS_OFF);
    bf16*  wp    = (bf16*) ((char*)d_ws + WPOOL_OFF);
    bf16*  t1    = (bf16*) ((char*)d_ws + BUF_OFF);
    bf16*  f1    = (bf16*) ((char*)d_ws + BUF_OFF + FEAT_BYTES);
    bf16*  offs  = (bf16*) ((char*)d_ws + BUF_OFF + 2*(size_t)FEAT_BYTES);
    bf16*  t0    = (bf16*) d_out;                       // d_out 1st half (scratch)
    bf16*  nbr_i = (bf16*)((char*)d_out + FEAT_BYTES);  // d_out 2nd half
    bf16*  refA  = offs;    // ref NHWC copy #1: offs region, dead until step 3
    bf16*  refB  = nbr_i;   // ref NHWC copy #2: nbr_i region, dead after step 4

    P20 a;
    for (int i = 0; i < 20; ++i){ a.p[i] = d_in[i]; a.n[i] = in_sizes[i]; }

    detect_kernel<<<1, 64, 0, stream>>>(a, flags);
    prep_bias<<<1, 256, 0, stream>>>(a, flags, bp);
    prep_convA<<<288, 256, 0, stream>>>(d_in[I_OC1W], flags, I_OC1W, wp+WA_OC1, 128, 64, 2);
    prep_convA<<<144, 256, 0, stream>>>(d_in[I_OC2W], flags, I_OC2W, wp+WA_OC2,  64, 64, 2);
    prep_convA<<<144, 256, 0, stream>>>(d_in[I_FCW],  flags, I_FCW,  wp+WA_FC,   64, 64, 2);
    prep_convA<<<288, 256, 0, stream>>>(d_in[I_C1W],  flags, I_C1W,  wp+WA_CAS1,128, 64, 2);
    prep_convA<<<144, 256, 0, stream>>>(d_in[I_C2W],  flags, I_C2W,  wp+WA_CAS2, 64, 64, 2);
    prep_convA<<<576, 256, 0, stream>>>(d_in[I_D1OW], flags, I_D1OW, wp+WA_D1O,  64, 216, 8);
    prep_convA<<<576, 256, 0, stream>>>(d_in[I_CDOW], flags, I_CDOW, wp+WA_CDO,  64, 216, 8);
    prep_projA<<<144, 256, 0, stream>>>(d_in[I_D1W],  flags, I_D1W,  wp+WP_D1);
    prep_projA<<<144, 256, 0, stream>>>(d_in[I_CDW],  flags, I_CDW,  wp+WP_CD);

    dim3 blk(256,1,1);
    const int smem64  = 3*66*68*2;    // 26928 B
    const int smem128 = 3*66*132*2;   // 52272 B
    dim3 gC (576, 1, Bn);             // all convs: 64px tiles, oc loop inside
    dim3 gD (576, Bn, 1);             // dcn: 24x24 8x8-px tiles
    dim3 gP (576, Bn, 1);

    // 0. NHWC packs: nbr -> nbr_i, ref -> refA (offs region, free until step 3)
    pack_x<<<gP, blk, 0, stream>>>(d_in[I_NBR], flags, I_NBR, nbr_i);
    pack_x<<<gP, blk, 0, stream>>>(d_in[I_REF], flags, I_REF, refA);
    // 1. t0 = lrelu(conv(cat(nbr,ref), oc1))   [NHWC]
    conv_mfma<<<gC, blk, smem128, stream>>>(nbr_i, refA, wp+WA_OC1, bp+B_OC1,
        t0, 1, 64, 64, 1);
    // 2. t1 = lrelu(conv(t0, oc2))             [NHWC]
    conv_mfma<<<gC, blk, smem64, stream>>>(t0, nullptr, wp+WA_OC2, bp+B_OC2,
        t1, 1, 64, 64, 1);
    // 3. offs = conv(t1, d1o)  [NCHW, masks sigmoided; overwrites refA (dead)]
    conv_mfma<<<gC, blk, smem64, stream>>>(t1, nullptr, wp+WA_D1O, bp+B_D1O,
        offs, 4, 216, 216, 2);
    // 4. t1 = dcn(x=nbr_i, offs; proj d1)      [NHWC out]
    dcn_mfma<<<gD, blk, 0, stream>>>(nbr_i, offs, wp+WP_D1, bp+B_D1P,
        t1, 0, 0);
    // 4b. refB = pack(ref) into nbr_i region (dead after step 4)
    pack_x<<<gP, blk, 0, stream>>>(d_in[I_REF], flags, I_REF, refB);
    // 5. f1 = conv(t1, fc)  (no act)           [NHWC]
    conv_mfma<<<gC, blk, smem64, stream>>>(t1, nullptr, wp+WA_FC, bp+B_FC,
        f1, 1, 64, 64, 0);
    // 6. t0 = lrelu(conv(cat(f1, ref), cas1))  [NHWC]
    conv_mfma<<<gC, blk, smem128, stream>>>(f1, refB, wp+WA_CAS1, bp+B_CAS1,
        t0, 1, 64, 64, 1);
    // 7. t1 = lrelu(conv(t0, cas2))            [NHWC]
    conv_mfma<<<gC, blk, smem64, stream>>>(t0, nullptr, wp+WA_CAS2, bp+B_CAS2,
        t1, 1, 64, 64, 1);
    // 8. offs = conv(t1, cdo)                  [NCHW, ACT=2]
    conv_mfma<<<gC, blk, smem64, stream>>>(t1, nullptr, wp+WA_CDO, bp+B_CDO,
        offs, 4, 216, 216, 2);
    // 9. d_out = lrelu(dcn(x=f1, offs; proj cd))  [NCHW fp32 final]
    dcn_mfma<<<gD, blk, 0, stream>>>(f1, offs, wp+WP_CD, bp+B_CDP,
        d_out, 1, 1);
}

// Round 7
// 858.567 us; speedup vs baseline: 3.0450x; 1.0409x over previous
//
#include <hip/hip_runtime.h>
#include <hip/hip_bf16.h>
#include <math.h>

typedef __hip_bfloat16 bf16;
typedef float  floatx16 __attribute__((ext_vector_type(16)));
typedef short  short8   __attribute__((ext_vector_type(8)));

#define Bn 4
#define NF 64
#define Hn 192
#define Wn 192
#define HWn (Hn*Wn)

// ---- weight pool element offsets (bf16 elements, relative to WPOOL) ----
#define WA_OC1  0
#define WA_OC2  73728
#define WA_FC   110592
#define WA_CAS1 147456
#define WA_CAS2 221184
#define WA_D1O  258048
#define WA_CDO  405504
#define WP_D1   552960
#define WP_CD   589824
// ---- bias pool float offsets ----
#define B_OC1  0
#define B_OC2  64
#define B_FC   128
#define B_CAS1 192
#define B_CAS2 256
#define B_D1O  320
#define B_CDO  536
#define B_D1P  752
#define B_CDP  816
// ---- ws byte offsets ----
#define BIAS_OFF  1024
#define WPOOL_OFF 5120
#define BUF_OFF   1261568          // 4K aligned, past weight pool
#define FEAT_BYTES 18874368        // 4*64*36864*2

// ---- dcn LDS geometry ----
#define WROWS 12
#define WCOLS 12
#define WSTR  72     // elems per window pixel (64ch + 8 pad) = 144 B
#define SSTR2 152    // elems per px in s_samp (18 slots*8 + 8 pad) = 304 B

__device__ __forceinline__ float b2f(bf16 v){ return __bfloat162float(v); }
__device__ __forceinline__ bf16  f2b(float v){ return __float2bfloat16(v); }
__device__ __forceinline__ float us2f(unsigned short u){ return __uint_as_float(((unsigned)u) << 16); }
__device__ __forceinline__ float ld(const void* p, size_t i, int f32){
    if (f32) return ((const float*)p)[i];
    return b2f(((const bf16*)p)[i]);
}

union B8 { uint2 u2[2]; uint4 u4; short8 s8; };
union V8 { uint4 u4; unsigned short us[8]; bf16 h[8]; };
union V4 { uint2 u2; bf16 h[4]; };

struct P20 { const void* p[20]; int n[20]; };

// ---------------------------------------------------------------------------
// Fused dtype probe + bias prep (1 block)
// ---------------------------------------------------------------------------
__global__ void detect_bias(P20 a, int* __restrict__ flags, float* __restrict__ bp){
    __shared__ int sf[20];
    int t = threadIdx.x;
    if (t < 20){
        const unsigned short* u = (const unsigned short*)a.p[t];
        int n = a.n[t]; if (n > 512) n = 512;
        int f32 = 0;
        for (int i = 0; i < n; ++i){
            float v = __uint_as_float(((unsigned)u[i]) << 16);
            if (!(fabsf(v) < 1e3f)) f32 = 1;
        }
        sf[t] = f32; flags[t] = f32;
    }
    __syncthreads();
    const int src[9] = {3,5,11,13,15,7,17,9,19};
    const int off[9] = {B_OC1,B_OC2,B_FC,B_CAS1,B_CAS2,B_D1O,B_CDO,B_D1P,B_CDP};
    const int sz[9]  = {64,64,64,64,64,216,216,64,64};
    for (int s = 0; s < 9; ++s)
        if (t < sz[s]) bp[off[s] + t] = ld(a.p[src[s]], t, sf[src[s]]);
}

// ---------------------------------------------------------------------------
// Fused weight prep: all 7 convA jobs + 2 projA jobs in one dispatch (2448 blk).
// convA: dst[((ocb*9+tap)*KK + kk)*512 + m*16 + ko*8 + j] = w[oc][ci][tap]
// projA: K permuted k' = (dg*9+tap)*8+cg ; original k = (dg*8+cg)*9+tap
// ---------------------------------------------------------------------------
__global__ void prep_weights(P20 a, const int* __restrict__ flags, bf16* __restrict__ wp)
{
    const int srcI[9] = {2,4,10,12,14,6,16,8,18};
    const int dstO[9] = {WA_OC1,WA_OC2,WA_FC,WA_CAS1,WA_CAS2,WA_D1O,WA_CDO,WP_D1,WP_CD};
    const int cinA[9] = {128,64,64,128,64,64,64,0,0};
    const int coutA[9]= {64,64,64,64,64,216,216,0,0};
    const int nblk[9] = {288,144,144,288,144,576,576,144,144};

    int bx = blockIdx.x;
    int j = 0, base = 0;
    while (j < 8 && bx >= base + nblk[j]){ base += nblk[j]; ++j; }
    int idx = (bx - base)*256 + threadIdx.x;
    const void* src = a.p[srcI[j]];
    const int f = flags[srcI[j]];
    bf16* dst = wp + dstO[j];

    int jj = idx & 7;
    int ko = (idx>>3) & 1;
    int mm = (idx>>4) & 31;
    int rest = idx >> 9;
    if (cinA[j]){
        int KK = cinA[j] >> 4;
        int kk = rest % KK; rest /= KK;
        int tap = rest % 9;
        int ocb = rest / 9;
        int oc = ocb*32 + mm;
        int ci = kk*16 + ko*8 + jj;
        float v = 0.f;
        if (oc < coutA[j]) v = ld(src, ((size_t)oc*cinA[j] + ci)*9 + tap, f);
        dst[idx] = f2b(v);
    } else {
        int kk = rest % 36;
        int ocb = rest / 36;
        int oc = ocb*32 + mm;
        int kp   = kk*16 + ko*8 + jj;
        int slot = kp >> 3;
        int cg   = kp & 7;
        int dg   = slot / 9;
        int tap  = slot - dg*9;
        int k    = (dg*8 + cg)*9 + tap;
        dst[idx] = f2b(ld(src, (size_t)oc*576 + k, f));
    }
}

// ---------------------------------------------------------------------------
// Pack: x [B][64][HW] (fp32 or bf16) -> NHWC [B][HW][64] bf16
// ---------------------------------------------------------------------------
__global__ __launch_bounds__(256)
void pack_x(const void* __restrict__ src, const int* __restrict__ flags, int fi,
            bf16* __restrict__ dst)
{
    __shared__ bf16 s[64*65];
    const int b    = blockIdx.y;
    const int pix0 = blockIdx.x * 64;
    const int t    = threadIdx.x;
    const int f    = (fi >= 0) ? flags[fi] : 0;

    const int px8 = (t & 7) * 8;
    const int ci0 = t >> 3;
#pragma unroll
    for (int it = 0; it < 2; ++it){
        int ci = ci0 + it*32;
        size_t g = ((size_t)b*NF + ci)*HWn + pix0 + px8;
        if (f){
            float4 a0 = *(const float4*)((const float*)src + g);
            float4 a1 = *(const float4*)((const float*)src + g + 4);
            bf16* sp = &s[ci*65 + px8];
            sp[0]=f2b(a0.x); sp[1]=f2b(a0.y); sp[2]=f2b(a0.z); sp[3]=f2b(a0.w);
            sp[4]=f2b(a1.x); sp[5]=f2b(a1.y); sp[6]=f2b(a1.z); sp[7]=f2b(a1.w);
        } else {
            V8 v; v.u4 = *(const uint4*)((const bf16*)src + g);
            bf16* sp = &s[ci*65 + px8];
#pragma unroll
            for (int j = 0; j < 8; ++j) sp[j] = v.h[j];
        }
    }
    __syncthreads();

    const int px  = t >> 2;
    const int ch0 = (t & 3) * 16;
    V8 o0, o1;
#pragma unroll
    for (int j = 0; j < 8; ++j){
        o0.h[j] = s[(ch0 + j)*65 + px];
        o1.h[j] = s[(ch0 + 8 + j)*65 + px];
    }
    bf16* dp = dst + ((size_t)b*HWn + pix0 + px)*64 + ch0;
    *(uint4*)(dp)     = o0.u4;
    *(uint4*)(dp + 8) = o1.u4;
}

// ---------------------------------------------------------------------------
// MFMA implicit-GEMM 3x3 conv, NHWC bf16, 2-row x 64-col tile (128 px/block).
// Wave w: oc-half (w>>1), row rw=(w&1); two 32-px subtiles -> 2 indep acc
// chains sharing every weight fragment. Ring-buffer weight prefetch (2x4
// uint4) hides L2 latency. KK templated: all tap/kk loops compile-time.
// ACT: 0/1 -> NHWC out (+lrelu); 2 -> NCHW 216-ch offs out, sigmoid oc>=144.
// ---------------------------------------------------------------------------
template<int KK, int NOCB>
__global__ __launch_bounds__(256, 2)
void conv_mfma(const bf16* __restrict__ inA, const bf16* __restrict__ inB,
               const bf16* __restrict__ wA, const float* __restrict__ bias,
               bf16* __restrict__ out, int ACT)
{
    constexpr int CinT  = KK*16;
    constexpr int ciPad = CinT + 4;          // 68/132: 136B row stride, 2-way-free b64
    constexpr int CH8   = CinT/8;            // 8 or 16 uint4 chunks per px
    constexpr int CSH   = (KK==4)?3:4;
    extern __shared__ __align__(16) char smem_raw[];
    bf16* s_in = (bf16*)smem_raw;

    const int b  = blockIdx.z;
    const int bx = blockIdx.x;
    const int ty = bx/3, tx = bx - ty*3;
    const int h0 = ty*2, x0 = tx*64;
    const int tid = threadIdx.x;

    // ---- stage 4 rows x 66 px x CinT ch (linear NHWC vector copies) ----
    for (int r = 0; r < 4; ++r){
        const int y = h0 - 1 + r;
        const bool yv = (unsigned)y < (unsigned)Hn;
        const size_t rb = ((size_t)b*HWn + (size_t)y*Wn)*64;
        for (int e = tid; e < 66*CH8; e += 256){
            const int c   = e >> CSH;
            const int ch8 = e & (CH8-1);
            const int x = x0 - 1 + c;
            B8 v; v.u4 = make_uint4(0,0,0,0);
            if (yv && (unsigned)x < (unsigned)Wn){
                if (KK==8 && ch8 >= 8) v.u4 = *(const uint4*)(inB + rb + (size_t)x*64 + (ch8-8)*8);
                else                   v.u4 = *(const uint4*)(inA + rb + (size_t)x*64 + ch8*8);
            }
            bf16* dp = &s_in[(size_t)(r*66 + c)*ciPad + ch8*8];
            *(uint2*)(dp)     = v.u2[0];
            *(uint2*)(dp + 4) = v.u2[1];
        }
    }
    __syncthreads();

    const int w    = tid >> 6;
    const int lane = tid & 63;
    const int m    = lane & 31;
    const int half = lane >> 5;
    const int och  = (w >> 1) * 32;
    const int rw   = (w & 1);                  // which of the 2 tile rows
    const int gpx0 = (h0 + rw)*Wn + x0;

#pragma unroll
    for (int ot = 0; ot < NOCB; ++ot){
        const int ocb = ot*2 + (w >> 1);
        const bf16* wb = wA + ((size_t)ocb*9*KK)*512 + m*16 + half*8;

        floatx16 a0, a1;
#pragma unroll
        for (int r = 0; r < 16; ++r){ a0[r] = 0.f; a1[r] = 0.f; }

        B8 ring[2][4];
#pragma unroll
        for (int i = 0; i < 4; ++i) ring[0][i].u4 = *(const uint4*)(wb + (size_t)i*512);

        constexpr int NCH = 9*KK/4;            // weight chunks (9 or 18)
#pragma unroll
        for (int tap = 0; tap < 9; ++tap){
            const int ky = tap/3, kx = tap - 3*(tap/3);
            const bf16* s0 = s_in + (size_t)((ky+rw)*66 + kx + m)*ciPad + half*8;
#pragma unroll
            for (int hh = 0; hh < KK/4; ++hh){
                const int cidx = tap*(KK/4) + hh;      // compile-time chunk idx
                const int cur = cidx & 1, nxt = cur ^ 1;
                if (cidx + 1 < NCH){
#pragma unroll
                    for (int i = 0; i < 4; ++i)
                        ring[nxt][i].u4 = *(const uint4*)(wb + (size_t)((cidx+1)*4 + i)*512);
                }
#pragma unroll
                for (int i = 0; i < 4; ++i){
                    const bf16* p0 = s0 + hh*64 + i*16;
                    const bf16* p1 = p0 + 32*ciPad;
                    B8 b0, b1;
                    b0.u2[0] = *(const uint2*)(p0); b0.u2[1] = *(const uint2*)(p0+4);
                    b1.u2[0] = *(const uint2*)(p1); b1.u2[1] = *(const uint2*)(p1+4);
                    a0 = __builtin_amdgcn_mfma_f32_32x32x16_bf16(ring[cur][i].s8, b0.s8, a0, 0,0,0);
                    a1 = __builtin_amdgcn_mfma_f32_32x32x16_bf16(ring[cur][i].s8, b1.s8, a1, 0,0,0);
                }
            }
        }

        // ---- epilogue ----
        if (ACT == 2){
#pragma unroll
            for (int s = 0; s < 2; ++s){
                const int px = gpx0 + s*32 + m;
#pragma unroll
                for (int r = 0; r < 16; ++r){
                    int row = (r & 3) + 8*(r >> 2) + 4*half;
                    int oc  = ot*64 + och + row;
                    if (oc < 216){
                        float v = (s ? a1[r] : a0[r]) + bias[oc];
                        if (oc >= 144) v = 1.f/(1.f + __expf(-v));
                        out[((size_t)b*216 + oc)*HWn + px] = f2b(v);
                    }
                }
            }
        } else {
#pragma unroll
            for (int s = 0; s < 2; ++s){
                const int px = gpx0 + s*32 + m;
                bf16* ob = out + ((size_t)b*HWn + px)*64 + och + 4*half;
#pragma unroll
                for (int q = 0; q < 4; ++q){
                    V4 u;
#pragma unroll
                    for (int j = 0; j < 4; ++j){
                        float v = (s ? a1[q*4+j] : a0[q*4+j]) + bias[och + 4*half + 8*q + j];
                        if (ACT == 1) v = (v >= 0.f) ? v : 0.1f*v;
                        u.h[j] = f2b(v);
                    }
                    *(uint2*)(ob + 8*q) = u.u2;
                }
            }
        }
    }
}

// ---------------------------------------------------------------------------
// DCN sample + MFMA projection, LDS-WINDOW GATHER (proven round 5/6).
// ---------------------------------------------------------------------------
__global__ __launch_bounds__(256, 2)
void dcn_mfma(const bf16* __restrict__ xi,     // NHWC [B][HW][64] bf16
              const bf16* __restrict__ offs,   // NCHW [B][216][HW] bf16 (masks sigmoided)
              const bf16* __restrict__ wP,     // A-frag layout, K permuted
              const float* __restrict__ pbias, // [64]
              void* __restrict__ out, int outF32, int ACT)
{
    __shared__ __align__(16) bf16 s_win[WROWS*WCOLS*WSTR];   // 20,736 B
    __shared__ __align__(16) bf16 s_samp[64*SSTR2];          // 19,456 B

    const int b   = blockIdx.y;
    const int bx  = blockIdx.x;
    const int tx  = bx % (Wn/8);
    const int ty  = bx / (Wn/8);
    const int gx0 = tx*8, gy0 = ty*8;
    const int wx0 = gx0 - 2, wy0 = gy0 - 2;
    const int tid = threadIdx.x;

    const bf16* xb = xi + (size_t)b*HWn*64;

    for (int c = tid; c < WROWS*WCOLS*8; c += 256){
        int ch4 = c & 7;
        int pxi = c >> 3;
        int gy  = wy0 + pxi/WCOLS;
        int gx  = wx0 + pxi%WCOLS;
        uint4 v = {0u,0u,0u,0u};
        if ((unsigned)gy < (unsigned)Hn && (unsigned)gx < (unsigned)Wn)
            v = *(const uint4*)(xb + ((size_t)gy*Wn + gx)*64 + ch4*8);
        *(uint4*)&s_win[pxi*WSTR + ch4*8] = v;
    }

    const int px   = tid & 63;
    const int wq   = tid >> 6;
    const int pr   = px >> 3, pc = px & 7;
    const int gy   = gy0 + pr, gx = gx0 + pc;
    const int m    = px & 31;
    const int half = px >> 5;
    const int och  = (wq >> 1) * 32;
    const int pxh  = (wq & 1) * 32;

    const size_t obase = (size_t)b*216*HWn + (size_t)gy*Wn + gx;
    const uint4 z4 = {0u,0u,0u,0u};

    const bf16* wPb  = wP + ((size_t)(wq>>1)*36)*512 + m*16 + half*8;
    const bf16* srow = s_samp + (pxh + m)*SSTR2 + half*8;

    floatx16 acc;
#pragma unroll
    for (int r = 0; r < 16; ++r) acc[r] = 0.f;

    for (int pass = 0; pass < 4; ++pass){
        __syncthreads();

#pragma unroll
        for (int ii = 0; ii < 5; ++ii){
            int sl = wq + ii*4;
            if (sl < 18){
                int dgl = sl / 9;
                int tap = sl - dgl*9;
                int dg  = pass*2 + dgl;
                int ky  = tap / 3;
                int kx  = tap - ky*3;
                float dy = b2f(offs[obase + (size_t)(dg*18 + tap*2    )*HWn]);
                float dx = b2f(offs[obase + (size_t)(dg*18 + tap*2 + 1)*HWn]);
                float mk = b2f(offs[obase + (size_t)(144 + dg*9 + tap )*HWn]);
                float py  = dy + (float)(gy - 1 + ky);
                float pxx = dx + (float)(gx - 1 + kx);
                float y0f = floorf(py), x0f = floorf(pxx);
                int   y0  = (int)y0f,   xi0 = (int)x0f;
                float wy  = py - y0f,   wx  = pxx - x0f;
                float w00 = (1.f-wy)*(1.f-wx)*mk, w01 = (1.f-wy)*wx*mk;
                float w10 = wy*(1.f-wx)*mk,       w11 = wy*wx*mk;
                int ly = y0 - wy0, lx = xi0 - wx0;

                auto fetch = [&](int ly_, int lx_, int y_, int x_) -> uint4 {
                    if ((unsigned)ly_ < (unsigned)WROWS && (unsigned)lx_ < (unsigned)WCOLS)
                        return *(const uint4*)&s_win[(ly_*WCOLS + lx_)*WSTR + dg*8];
                    if ((unsigned)y_ < (unsigned)Hn && (unsigned)x_ < (unsigned)Wn)
                        return *(const uint4*)(xb + ((size_t)y_*Wn + x_)*64 + dg*8);
                    return z4;
                };
                V8 c00, c01, c10, c11, o;
                c00.u4 = fetch(ly,   lx,   y0,   xi0  );
                c01.u4 = fetch(ly,   lx+1, y0,   xi0+1);
                c10.u4 = fetch(ly+1, lx,   y0+1, xi0  );
                c11.u4 = fetch(ly+1, lx+1, y0+1, xi0+1);
#pragma unroll
                for (int j = 0; j < 8; ++j){
                    float v = w00*us2f(c00.us[j]) + w01*us2f(c01.us[j])
                            + w10*us2f(c10.us[j]) + w11*us2f(c11.us[j]);
                    o.h[j] = f2b(v);
                }
                *(uint4*)&s_samp[px*SSTR2 + sl*8] = o.u4;
            }
        }
        __syncthreads();

#pragma unroll
        for (int kk = 0; kk < 9; ++kk){
            B8 ba; ba.u4 = *(const uint4*)(wPb + (size_t)(pass*9 + kk)*512);
            B8 bb; bb.u4 = *(const uint4*)(srow + kk*16);
            acc = __builtin_amdgcn_mfma_f32_32x32x16_bf16(ba.s8, bb.s8, acc, 0, 0, 0);
        }
    }

    const int opx = pxh + m;
    const int pxo = (gy0 + (opx >> 3))*Wn + gx0 + (opx & 7);
    if (outF32){
#pragma unroll
        for (int r = 0; r < 16; ++r){
            int row = (r & 3) + 8*(r >> 2) + 4*half;
            int oc  = och + row;
            float v = acc[r] + pbias[oc];
            if (ACT) v = (v >= 0.f) ? v : 0.1f*v;
            ((float*)out)[((size_t)b*NF + oc)*HWn + pxo] = v;
        }
    } else {
        bf16* ob = (bf16*)out + ((size_t)b*HWn + pxo)*64 + och + 4*half;
#pragma unroll
        for (int q = 0; q < 4; ++q){
            V4 u;
#pragma unroll
            for (int j = 0; j < 4; ++j){
                int oc = och + 4*half + 8*q + j;
                float v = acc[q*4 + j] + pbias[oc];
                if (ACT) v = (v >= 0.f) ? v : 0.1f*v;
                u.h[j] = f2b(v);
            }
            *(uint2*)(ob + 8*q) = u.u2;
        }
    }
}

// ---------------------------------------------------------------------------
extern "C" void kernel_launch(void* const* d_in, const int* in_sizes, int n_in,
                              void* d_out, int out_size, void* d_ws, size_t ws_size,
                              hipStream_t stream)
{
    enum { I_NBR=0, I_REF=1 };

    int*   flags = (int*)d_ws;
    float* bp    = (float*)((char*)d_ws + BIAS_OFF);
    bf16*  wp    = (bf16*) ((char*)d_ws + WPOOL_OFF);
    bf16*  t1    = (bf16*) ((char*)d_ws + BUF_OFF);
    bf16*  f1    = (bf16*) ((char*)d_ws + BUF_OFF + FEAT_BYTES);
    bf16*  offs  = (bf16*) ((char*)d_ws + BUF_OFF + 2*(size_t)FEAT_BYTES);
    bf16*  t0    = (bf16*) d_out;                       // d_out 1st half (scratch)
    bf16*  nbr_i = (bf16*)((char*)d_out + FEAT_BYTES);  // d_out 2nd half
    bf16*  refA  = offs;    // ref NHWC copy #1: offs region, dead until step 3
    bf16*  refB  = nbr_i;   // ref NHWC copy #2: nbr_i region, dead after step 4

    P20 a;
    for (int i = 0; i < 20; ++i){ a.p[i] = d_in[i]; a.n[i] = in_sizes[i]; }

    detect_bias<<<1, 256, 0, stream>>>(a, flags, bp);
    prep_weights<<<2448, 256, 0, stream>>>(a, flags, wp);

    dim3 blk(256,1,1);
    const int smem64  = 4*66*68*2;    // 35,904 B
    const int smem128 = 4*66*132*2;   // 69,696 B
    dim3 gC (288, 1, Bn);             // 96 row-pairs x 3 col-tiles
    dim3 gD (576, Bn, 1);             // dcn: 24x24 8x8-px tiles
    dim3 gP (576, Bn, 1);

    // 0. NHWC packs: nbr -> nbr_i, ref -> refA (offs region, free until step 3)
    pack_x<<<gP, blk, 0, stream>>>(d_in[I_NBR], flags, I_NBR, nbr_i);
    pack_x<<<gP, blk, 0, stream>>>(d_in[I_REF], flags, I_REF, refA);
    // 1. t0 = lrelu(conv(cat(nbr,ref), oc1))   [NHWC]
    conv_mfma<8,1><<<gC, blk, smem128, stream>>>(nbr_i, refA, wp+WA_OC1, bp+B_OC1, t0, 1);
    // 2. t1 = lrelu(conv(t0, oc2))             [NHWC]
    conv_mfma<4,1><<<gC, blk, smem64, stream>>>(t1==t1?t0:t0, nullptr, wp+WA_OC2, bp+B_OC2, t1, 1);
    // 3. offs = conv(t1, d1o)  [NCHW, masks sigmoided; overwrites refA (dead)]
    conv_mfma<4,4><<<gC, blk, smem64, stream>>>(t1, nullptr, wp+WA_D1O, bp+B_D1O, offs, 2);
    // 4. t1 = dcn(x=nbr_i, offs; proj d1)      [NHWC out]
    dcn_mfma<<<gD, blk, 0, stream>>>(nbr_i, offs, wp+WP_D1, bp+B_D1P, t1, 0, 0);
    // 4b. refB = pack(ref) into nbr_i region (dead after step 4)
    pack_x<<<gP, blk, 0, stream>>>(d_in[I_REF], flags, I_REF, refB);
    // 5. f1 = conv(t1, fc)  (no act)           [NHWC]
    conv_mfma<4,1><<<gC, blk, smem64, stream>>>(t1, nullptr, wp+WA_FC, bp+B_FC, f1, 0);
    // 6. t0 = lrelu(conv(cat(f1, ref), cas1))  [NHWC]
    conv_mfma<8,1><<<gC, blk, smem128, stream>>>(f1, refB, wp+WA_CAS1, bp+B_CAS1, t0, 1);
    // 7. t1 = lrelu(conv(t0, cas2))            [NHWC]
    conv_mfma<4,1><<<gC, blk, smem64, stream>>>(t0, nullptr, wp+WA_CAS2, bp+B_CAS2, t1, 1);
    // 8. offs = conv(t1, cdo)                  [NCHW, ACT=2]
    conv_mfma<4,4><<<gC, blk, smem64, stream>>>(t1, nullptr, wp+WA_CDO, bp+B_CDO, offs, 2);
    // 9. d_out = lrelu(dcn(x=f1, offs; proj cd))  [NCHW fp32 final]
    dcn_mfma<<<gD, blk, 0, stream>>>(f1, offs, wp+WP_CD, bp+B_CDP, d_out, 1, 1);
}